// Round 2
// baseline (568.408 us; speedup 1.0000x reference)
//
#include <hip/hip_runtime.h>
#include <hip/hip_bf16.h>
#include <math.h>

#define DEV __device__ __forceinline__

static constexpr int LL = 4096;   // H*W
static constexpr int DD = 128;    // hidden

DEV float silu_(float x) { return x / (1.f + __expf(-x)); }
DEV float softplus_(float x) { return fmaxf(x, 0.f) + log1pf(__expf(-fabsf(x))); }
DEV float gelu_(float x) { return 0.5f * x * (1.f + erff(x * 0.7071067811865475f)); }

template <int CTRL>
DEV float dpp_add_(float x) {
  int y = __builtin_amdgcn_update_dpp(0, __float_as_int(x), CTRL, 0xF, 0xF, true);
  return x + __int_as_float(y);
}

// scan-position -> hw-position map (same map gathers xs and scatters y)
DEV int phys_idx(int k, int l) {
  if (k == 0) return l;
  if (k == 1) return ((l & 63) << 6) | (l >> 6);
  if (k == 2) return 4095 - l;
  int l2 = 4095 - l;
  return ((l2 & 63) << 6) | (l2 >> 6);
}

// ---------------- K1: in_proj: xz[m][b][c][l] = x @ in_w^T (c-major out) ----
__global__ __launch_bounds__(256) void k_inproj(
    const float* __restrict__ sar, const float* __restrict__ opt,
    const float* __restrict__ in_w, float* __restrict__ xz) {
  const int lt = blockIdx.x, ct = blockIdx.y, mb = blockIdx.z;
  const int m = mb >> 2;
  const float* __restrict__ x = (m == 0 ? opt : sar) + (size_t)(mb & 3) * (LL * DD);
  const float* __restrict__ W = in_w + (size_t)m * 256 * DD;
  __shared__ float sA[64][68];
  __shared__ float sW[64][68];
  const int tid = threadIdx.x;
  const int tc = tid & 15, tl = tid >> 4;
  float acc[4][4] = {};
  for (int db = 0; db < 2; ++db) {
    __syncthreads();
    for (int idx = tid; idx < 64 * 64; idx += 256) {
      const int r = idx >> 6, d = idx & 63;
      sA[r][d] = x[(size_t)(lt * 64 + r) * DD + db * 64 + d];
      sW[r][d] = W[(size_t)(ct * 64 + r) * DD + db * 64 + d];
    }
    __syncthreads();
#pragma unroll 4
    for (int d = 0; d < 64; d += 4) {
      float4 a[4], w[4];
#pragma unroll
      for (int q = 0; q < 4; ++q) a[q] = *(const float4*)&sA[tl * 4 + q][d];
#pragma unroll
      for (int j = 0; j < 4; ++j) w[j] = *(const float4*)&sW[tc + 16 * j][d];
#pragma unroll
      for (int j = 0; j < 4; ++j)
#pragma unroll
        for (int q = 0; q < 4; ++q)
          acc[j][q] += a[q].x * w[j].x + a[q].y * w[j].y + a[q].z * w[j].z + a[q].w * w[j].w;
    }
  }
  float* __restrict__ dst = xz + ((size_t)mb * 256 + ct * 64) * LL + lt * 64;
#pragma unroll
  for (int j = 0; j < 4; ++j) {
    float4 v = make_float4(acc[j][0], acc[j][1], acc[j][2], acc[j][3]);
    *(float4*)&dst[(size_t)(tc + 16 * j) * LL + tl * 4] = v;
  }
}

// ---------------- K2: depthwise 3x3 SAME conv + bias + SiLU ---------------
// in: xz channels 0..127 as [m][b][d][h][w]; out: xc[m][b][l][d]
__global__ __launch_bounds__(256) void k_conv(
    const float* __restrict__ xz, const float* __restrict__ conv_w,
    const float* __restrict__ conv_b, float* __restrict__ xc) {
  const int ht = blockIdx.x, dg = blockIdx.y, mb = blockIdx.z;
  const int m = mb >> 2;
  __shared__ float sIn[8][18][66];
  const float* __restrict__ src = xz + ((size_t)mb * 256 + dg * 8) * LL;
  const int tid = threadIdx.x;
  for (int idx = tid; idx < 8 * 18 * 66; idx += 256) {
    const int dd = idx / (18 * 66);
    const int rem = idx - dd * (18 * 66);
    const int hh = rem / 66, ww = rem - hh * 66;
    const int h = ht * 16 + hh - 1, w = ww - 1;
    float v = 0.f;
    if (h >= 0 && h < 64 && w >= 0 && w < 64) v = src[(size_t)dd * LL + h * 64 + w];
    sIn[dd][hh][ww] = v;
  }
  __syncthreads();
  const int dd = tid & 7, wv = tid >> 3;
  const int dch = dg * 8 + dd;
  float wk[9];
#pragma unroll
  for (int t = 0; t < 9; ++t) wk[t] = conv_w[((size_t)m * DD + dch) * 9 + t];
  const float bias = conv_b[m * DD + dch];
  for (int hh = 0; hh < 16; ++hh) {
#pragma unroll
    for (int wh = 0; wh < 2; ++wh) {
      const int w = wv + wh * 32;
      float s = bias;
#pragma unroll
      for (int kh = 0; kh < 3; ++kh)
#pragma unroll
        for (int kw = 0; kw < 3; ++kw)
          s = fmaf(sIn[dd][hh + kh][w + kw], wk[kh * 3 + kw], s);
      s = silu_(s);
      const int l = (ht * 16 + hh) * 64 + w;
      xc[((size_t)mb * LL + l) * DD + dch] = s;
    }
  }
}

// ---------------- K3: x_proj: xdbl[m][b][k][c=24][l] ----------------------
__global__ __launch_bounds__(256) void k_xproj(
    const float* __restrict__ xc, const float* __restrict__ xproj_w,
    float* __restrict__ xdbl) {
  const int lt = blockIdx.x, k = blockIdx.y, mb = blockIdx.z;
  const int m = mb >> 2;
  __shared__ float sX[64][132];
  __shared__ float sW[24][132];
  const int tid = threadIdx.x;
  const float* __restrict__ src = xc + (size_t)mb * LL * DD;
  for (int idx = tid; idx < 64 * 128; idx += 256) {
    const int l = idx >> 7, d = idx & 127;
    sX[l][d] = src[(size_t)phys_idx(k, lt * 64 + l) * DD + d];
  }
  const float* __restrict__ Wsrc = xproj_w + ((size_t)m * 4 + k) * 24 * DD;
  for (int idx = tid; idx < 24 * 128; idx += 256) sW[idx >> 7][idx & 127] = Wsrc[idx];
  __syncthreads();
  const int l = tid >> 2, cg = tid & 3;
  float acc[6] = {};
#pragma unroll 8
  for (int d = 0; d < 128; d += 4) {
    const float4 xv = *(const float4*)&sX[l][d];
#pragma unroll
    for (int j = 0; j < 6; ++j) {
      const float4 wv = *(const float4*)&sW[cg * 6 + j][d];
      acc[j] += xv.x * wv.x + xv.y * wv.y + xv.z * wv.z + xv.w * wv.w;
    }
  }
  float* __restrict__ dst = xdbl + ((size_t)mb * 4 + k) * 24 * LL + lt * 64 + l;
#pragma unroll
  for (int j = 0; j < 6; ++j) dst[(size_t)(cg * 6 + j) * LL] = acc[j];
}

// ---------------- K4: dt = softplus(dts @ dt_w^T + dt_b): dt[m][b][k][d][l]
__global__ __launch_bounds__(256) void k_dtproj(
    const float* __restrict__ xdbl, const float* __restrict__ dt_w,
    const float* __restrict__ dt_b, float* __restrict__ dtb) {
  const int lt = blockIdx.x, k = blockIdx.y, mb = blockIdx.z;
  const int m = mb >> 2;
  __shared__ float sD[8][256];
  __shared__ float sW[128][8];
  __shared__ float sB[128];
  const int tid = threadIdx.x;
  const float* __restrict__ src = xdbl + ((size_t)mb * 4 + k) * 24 * LL + lt * 256;
  for (int idx = tid; idx < 8 * 256; idx += 256) {
    const int r = idx >> 8, l = idx & 255;
    sD[r][l] = src[(size_t)r * LL + l];
  }
  const float* __restrict__ wsrc = dt_w + ((size_t)m * 4 + k) * DD * 8;
  for (int idx = tid; idx < DD * 8; idx += 256) sW[idx >> 3][idx & 7] = wsrc[idx];
  if (tid < DD) sB[tid] = dt_b[((size_t)m * 4 + k) * DD + tid];
  __syncthreads();
  const float r0 = sD[0][tid], r1 = sD[1][tid], r2 = sD[2][tid], r3 = sD[3][tid];
  const float r4 = sD[4][tid], r5 = sD[5][tid], r6 = sD[6][tid], r7 = sD[7][tid];
  float* __restrict__ dst = dtb + (((size_t)mb * 4 + k) * DD) * LL + lt * 256 + tid;
  for (int d = 0; d < DD; ++d) {
    const float4 wa = *(const float4*)&sW[d][0];
    const float4 wb = *(const float4*)&sW[d][4];
    float s = sB[d];
    s = fmaf(r0, wa.x, s); s = fmaf(r1, wa.y, s); s = fmaf(r2, wa.z, s); s = fmaf(r3, wa.w, s);
    s = fmaf(r4, wb.x, s); s = fmaf(r5, wb.y, s); s = fmaf(r6, wb.z, s); s = fmaf(r7, wb.w, s);
    dst[(size_t)d * LL] = softplus_(s);
  }
}

// ---------------- K5: selective scan, 4 directions summed into ysum -------
// block: 128 thr = 16 d x 8 n; grid (dg=8, k=4, mb=8)
__global__ __launch_bounds__(128) void k_scan(
    const float* __restrict__ xc, const float* __restrict__ xdbl,
    const float* __restrict__ dtb, const float* __restrict__ Alogs,
    const float* __restrict__ Ds, float* __restrict__ ysum) {
  const int dg = blockIdx.x, k = blockIdx.y, mb = blockIdx.z;
  const int m = mb >> 2;
  const int tid = threadIdx.x;
  __shared__ float2 sdx[16][65];  // [dd][l] = (dt, x)
  __shared__ float2 sbc[8][65];   // [n][l]  = (B, C)
  __shared__ float ybuf[64][17];
  const int n = tid & 7, dd = (tid >> 3) & 15;
  const int d = dg * 16 + dd;
  const float a = -__expf(Alogs[((size_t)m * 512 + k * DD + d) * 8 + n]);
  const float aln2 = a * 1.4426950408889634f;  // pre-scale for exp2
  const float dsv = Ds[(size_t)m * 512 + k * DD + d];
  const float* __restrict__ dtsrc = dtb + (((size_t)mb * 4 + k) * DD + dg * 16) * LL;
  const float* __restrict__ bcsrc = xdbl + (((size_t)mb * 4 + k) * 24 + 8) * LL;
  const float* __restrict__ xsrc = xc + (size_t)mb * LL * DD + dg * 16;
  float* __restrict__ ydst = ysum + (size_t)mb * LL * DD;
  float h = 0.f;
  float pdt[8], px[8], pbc[8];

  auto stage_load = [&](int c0) {
    const int l0 = c0 * 64;
#pragma unroll
    for (int j = 0; j < 8; ++j) {
      const int idx = tid + j * 128;
      const int r = idx >> 6, l = idx & 63;
      pdt[j] = dtsrc[(size_t)r * LL + l0 + l];
      pbc[j] = bcsrc[(size_t)r * LL + l0 + l];
      const int lx = idx >> 4, rx = idx & 15;
      px[j] = xsrc[(size_t)phys_idx(k, l0 + lx) * DD + rx];
    }
  };
  auto stage_store = [&]() {
#pragma unroll
    for (int j = 0; j < 8; ++j) {
      const int idx = tid + j * 128;
      const int r = idx >> 6, l = idx & 63;
      sdx[r][l].x = pdt[j];
      if (r < 8) sbc[r][l].x = pbc[j]; else sbc[r - 8][l].y = pbc[j];
      const int lx = idx >> 4, rx = idx & 15;
      sdx[rx][lx].y = px[j];
    }
  };

  stage_load(0);
  stage_store();
  __syncthreads();
  for (int c0 = 0; c0 < 64; ++c0) {
    if (c0 + 1 < 64) stage_load(c0 + 1);  // in flight during scan (T14)
#pragma unroll 8
    for (int l = 0; l < 64; ++l) {
      const float2 dx = sdx[dd][l];
      const float2 bc = sbc[n][l];
      const float e = __builtin_amdgcn_exp2f(dx.x * aln2);
      h = fmaf(h, e, dx.x * dx.y * bc.x);
      float p = h * bc.y;
      p = dpp_add_<0xB1>(p);   // xor1 (quad_perm 1,0,3,2)
      p = dpp_add_<0x4E>(p);   // xor2 (quad_perm 2,3,0,1)
      p = dpp_add_<0x141>(p);  // row_half_mirror -> cross-quad within octet
      ybuf[l][dd] = fmaf(dsv, dx.y, p);
    }
    __syncthreads();
    {
      const int fd = tid & 15, fl = tid >> 4;
      const int l0 = c0 * 64;
#pragma unroll
      for (int j2 = 0; j2 < 8; ++j2) {
        const int l = fl + j2 * 8;
        const int lhw = phys_idx(k, l0 + l);
        unsafeAtomicAdd(&ydst[(size_t)lhw * DD + dg * 16 + fd], ybuf[l][fd]);
      }
    }
    if (c0 + 1 < 64) stage_store();
    __syncthreads();
  }
}

// ---------------- K6: LN(y) * silu(z) @ out_w^T -> guided[m][b][l][d] -----
__global__ __launch_bounds__(256) void k_outproj(
    const float* __restrict__ ysum, const float* __restrict__ xz,
    const float* __restrict__ ln_g, const float* __restrict__ ln_b,
    const float* __restrict__ out_w, float* __restrict__ guided) {
  const int lt = blockIdx.x, mb = blockIdx.y;
  const int m = mb >> 2;
  __shared__ float sv[64][132];
  __shared__ float sW[64][68];
  __shared__ float smr[64][2];
  __shared__ float sg[128], sb[128];
  const int tid = threadIdx.x;
  if (tid < 128) { sg[tid] = ln_g[m * DD + tid]; sb[tid] = ln_b[m * DD + tid]; }
  const float* __restrict__ ysrc = ysum + ((size_t)mb * LL + lt * 64) * DD;
  for (int idx = tid; idx < 64 * 128; idx += 256) sv[idx >> 7][idx & 127] = ysrc[idx];
  __syncthreads();
  {
    const int l = tid >> 2, q = tid & 3;
    float s = 0.f, s2 = 0.f;
#pragma unroll
    for (int d0 = 0; d0 < 32; d0 += 4) {
      const float4 v = *(const float4*)&sv[l][q * 32 + d0];
      s += v.x + v.y + v.z + v.w;
      s2 += v.x * v.x + v.y * v.y + v.z * v.z + v.w * v.w;
    }
    s = dpp_add_<0xB1>(s); s = dpp_add_<0x4E>(s);
    s2 = dpp_add_<0xB1>(s2); s2 = dpp_add_<0x4E>(s2);
    if (q == 0) {
      const float mean = s * (1.f / 128.f);
      smr[l][0] = mean;
      smr[l][1] = rsqrtf(fmaf(s2, 1.f / 128.f, -mean * mean) + 1e-5f);
    }
  }
  __syncthreads();
  {
    const int c = tid >> 1, half = tid & 1;
    const float* __restrict__ zsrc = xz + ((size_t)mb * 256 + 128 + c) * LL + lt * 64 + half * 32;
    const float g = sg[c], bb = sb[c];
#pragma unroll
    for (int i = 0; i < 32; i += 4) {
      const float4 z4 = *(const float4*)&zsrc[i];
      const float zz[4] = {z4.x, z4.y, z4.z, z4.w};
#pragma unroll
      for (int t = 0; t < 4; ++t) {
        const int l = half * 32 + i + t;
        const float v = fmaf((sv[l][c] - smr[l][0]) * smr[l][1], g, bb);
        sv[l][c] = v * silu_(zz[t]);
      }
    }
  }
  const int tc = tid & 15, tl = tid >> 4;
  const float* __restrict__ Wp = out_w + (size_t)m * DD * DD;
  float* __restrict__ dst = guided + ((size_t)mb * LL + lt * 64) * DD;
  for (int jb = 0; jb < 2; ++jb) {
    float acc[4][4] = {};
    for (int db = 0; db < 2; ++db) {
      __syncthreads();
      for (int idx = tid; idx < 64 * 64; idx += 256) {
        const int r = idx >> 6, dcol = idx & 63;
        sW[r][dcol] = Wp[(size_t)(jb * 64 + r) * DD + db * 64 + dcol];
      }
      __syncthreads();
#pragma unroll 4
      for (int d0 = 0; d0 < 64; d0 += 4) {
        float4 av[4], wv[4];
#pragma unroll
        for (int q = 0; q < 4; ++q) av[q] = *(const float4*)&sv[tl * 4 + q][db * 64 + d0];
#pragma unroll
        for (int j = 0; j < 4; ++j) wv[j] = *(const float4*)&sW[tc + 16 * j][d0];
#pragma unroll
        for (int j = 0; j < 4; ++j)
#pragma unroll
          for (int q = 0; q < 4; ++q)
            acc[j][q] += av[q].x * wv[j].x + av[q].y * wv[j].y + av[q].z * wv[j].z + av[q].w * wv[j].w;
      }
    }
#pragma unroll
    for (int j = 0; j < 4; ++j)
#pragma unroll
      for (int q = 0; q < 4; ++q)
        dst[(size_t)(tl * 4 + q) * DD + jb * 64 + tc + 16 * j] = acc[j][q];
  }
}

// ---------------- K7: enhance (LN -> GEMM -> +bias -> GELU -> +residual) --
__global__ __launch_bounds__(256) void k_enhance(
    const float* __restrict__ guided, const float* __restrict__ eg,
    const float* __restrict__ ebv, const float* __restrict__ ew,
    const float* __restrict__ ebias, const float* __restrict__ sar,
    const float* __restrict__ opt, float* __restrict__ outp) {
  const int lt = blockIdx.x, ib = blockIdx.y;
  const int i = ib >> 2, b = ib & 3;
  __shared__ float sv[64][132];
  __shared__ float sW[64][68];
  __shared__ float smr[64][2];
  __shared__ float sg[128], sb2[128], sbias[128];
  const int tid = threadIdx.x;
  if (tid < 128) {
    sg[tid] = eg[i * DD + tid];
    sb2[tid] = ebv[i * DD + tid];
    sbias[tid] = ebias[i * DD + tid];
  }
  const float* __restrict__ gsrc = guided + (((size_t)(1 - i) * 4 + b) * LL + lt * 64) * DD;
  for (int idx = tid; idx < 64 * 128; idx += 256) sv[idx >> 7][idx & 127] = gsrc[idx];
  __syncthreads();
  {
    const int l = tid >> 2, q = tid & 3;
    float s = 0.f, s2 = 0.f;
#pragma unroll
    for (int d0 = 0; d0 < 32; d0 += 4) {
      const float4 v = *(const float4*)&sv[l][q * 32 + d0];
      s += v.x + v.y + v.z + v.w;
      s2 += v.x * v.x + v.y * v.y + v.z * v.z + v.w * v.w;
    }
    s = dpp_add_<0xB1>(s); s = dpp_add_<0x4E>(s);
    s2 = dpp_add_<0xB1>(s2); s2 = dpp_add_<0x4E>(s2);
    if (q == 0) {
      const float mean = s * (1.f / 128.f);
      smr[l][0] = mean;
      smr[l][1] = rsqrtf(fmaf(s2, 1.f / 128.f, -mean * mean) + 1e-5f);
    }
  }
  __syncthreads();
  {
    const int c = tid >> 1, half = tid & 1;
    const float g = sg[c], bb = sb2[c];
#pragma unroll
    for (int i2 = 0; i2 < 32; ++i2) {
      const int l = half * 32 + i2;
      sv[l][c] = fmaf((sv[l][c] - smr[l][0]) * smr[l][1], g, bb);
    }
  }
  const int tc = tid & 15, tl = tid >> 4;
  const float* __restrict__ Wp = ew + (size_t)i * DD * DD;
  const float* __restrict__ resid = (i == 0 ? sar : opt) + ((size_t)b * LL + lt * 64) * DD;
  float* __restrict__ dst = outp + (size_t)i * (4 * LL * DD) + ((size_t)b * LL + lt * 64) * DD;
  for (int jb = 0; jb < 2; ++jb) {
    float acc[4][4] = {};
    for (int db = 0; db < 2; ++db) {
      __syncthreads();
      for (int idx = tid; idx < 64 * 64; idx += 256) {
        const int r = idx >> 6, dcol = idx & 63;
        sW[r][dcol] = Wp[(size_t)(jb * 64 + r) * DD + db * 64 + dcol];
      }
      __syncthreads();
#pragma unroll 4
      for (int d0 = 0; d0 < 64; d0 += 4) {
        float4 av[4], wv[4];
#pragma unroll
        for (int q = 0; q < 4; ++q) av[q] = *(const float4*)&sv[tl * 4 + q][db * 64 + d0];
#pragma unroll
        for (int j = 0; j < 4; ++j) wv[j] = *(const float4*)&sW[tc + 16 * j][d0];
#pragma unroll
        for (int j = 0; j < 4; ++j)
#pragma unroll
          for (int q = 0; q < 4; ++q)
            acc[j][q] += av[q].x * wv[j].x + av[q].y * wv[j].y + av[q].z * wv[j].z + av[q].w * wv[j].w;
      }
    }
#pragma unroll
    for (int j = 0; j < 4; ++j)
#pragma unroll
      for (int q = 0; q < 4; ++q) {
        const int col = jb * 64 + tc + 16 * j;
        const int row = tl * 4 + q;
        const float u = acc[j][q] + sbias[col];
        dst[(size_t)row * DD + col] = resid[(size_t)row * DD + col] + gelu_(u);
      }
  }
}

extern "C" void kernel_launch(void* const* d_in, const int* in_sizes, int n_in,
                              void* d_out, int out_size, void* d_ws, size_t ws_size,
                              hipStream_t stream) {
  (void)in_sizes; (void)n_in; (void)out_size; (void)ws_size;
  const float* sar    = (const float*)d_in[0];
  const float* opt    = (const float*)d_in[1];
  const float* in_w   = (const float*)d_in[2];
  const float* conv_w = (const float*)d_in[3];
  const float* conv_b = (const float*)d_in[4];
  const float* xproj_w= (const float*)d_in[5];
  const float* dt_w   = (const float*)d_in[6];
  const float* dt_b   = (const float*)d_in[7];
  const float* Alogs  = (const float*)d_in[8];
  const float* Ds     = (const float*)d_in[9];
  const float* ln_g   = (const float*)d_in[10];
  const float* ln_b   = (const float*)d_in[11];
  const float* out_w  = (const float*)d_in[12];
  const float* eg     = (const float*)d_in[13];
  const float* eb     = (const float*)d_in[14];
  const float* ew     = (const float*)d_in[15];
  const float* ebias  = (const float*)d_in[16];

  float* ws     = (float*)d_ws;
  float* xz     = ws;                  // 2*4*256*4096   = 8,388,608
  float* xc     = xz + 8388608;        // 2*4*4096*128   = 4,194,304
  float* xdbl   = xc + 4194304;        // 2*4*4*24*4096  = 3,145,728
  float* dtb    = xdbl + 3145728;      // 2*4*4*128*4096 = 16,777,216
  float* ysumb  = dtb + 16777216;      // 2*4*4096*128   = 4,194,304
  float* guided = ysumb + 4194304;     // 2*4*4096*128   = 4,194,304
  float* outf   = (float*)d_out;

  hipMemsetAsync(ysumb, 0, (size_t)4194304 * sizeof(float), stream);
  k_inproj <<<dim3(64, 4, 8), 256, 0, stream>>>(sar, opt, in_w, xz);
  k_conv   <<<dim3(4, 16, 8), 256, 0, stream>>>(xz, conv_w, conv_b, xc);
  k_xproj  <<<dim3(64, 4, 8), 256, 0, stream>>>(xc, xproj_w, xdbl);
  k_dtproj <<<dim3(16, 4, 8), 256, 0, stream>>>(xdbl, dt_w, dt_b, dtb);
  k_scan   <<<dim3(8, 4, 8), 128, 0, stream>>>(xc, xdbl, dtb, Alogs, Ds, ysumb);
  k_outproj<<<dim3(64, 8), 256, 0, stream>>>(ysumb, xz, ln_g, ln_b, out_w, guided);
  k_enhance<<<dim3(64, 8), 256, 0, stream>>>(guided, eg, eb, ew, ebias, sar, opt, outf);
}

// Round 3
// 436.017 us; speedup vs baseline: 1.3036x; 1.3036x over previous
//
#include <hip/hip_runtime.h>
#include <hip/hip_bf16.h>
#include <math.h>

#define DEV __device__ __forceinline__

static constexpr int LL = 4096;   // H*W
static constexpr int DD = 128;    // hidden

DEV float silu_(float x) { return x / (1.f + __expf(-x)); }
DEV float softplus_(float x) { return fmaxf(x, 0.f) + log1pf(__expf(-fabsf(x))); }
DEV float gelu_(float x) { return 0.5f * x * (1.f + erff(x * 0.7071067811865475f)); }

template <int CTRL>
DEV float dpp_add_(float x) {
  int y = __builtin_amdgcn_update_dpp(0, __float_as_int(x), CTRL, 0xF, 0xF, true);
  return x + __int_as_float(y);
}

// scan-position -> hw-position map (same map gathers xs and scatters y)
DEV int phys_idx(int k, int l) {
  if (k == 0) return l;
  if (k == 1) return ((l & 63) << 6) | (l >> 6);
  if (k == 2) return 4095 - l;
  int l2 = 4095 - l;
  return ((l2 & 63) << 6) | (l2 >> 6);
}

// ---------------- K1: in_proj: xz[m][b][c][l] = x @ in_w^T (c-major out) ----
__global__ __launch_bounds__(256) void k_inproj(
    const float* __restrict__ sar, const float* __restrict__ opt,
    const float* __restrict__ in_w, float* __restrict__ xz) {
  const int lt = blockIdx.x, ct = blockIdx.y, mb = blockIdx.z;
  const int m = mb >> 2;
  const float* __restrict__ x = (m == 0 ? opt : sar) + (size_t)(mb & 3) * (LL * DD);
  const float* __restrict__ W = in_w + (size_t)m * 256 * DD;
  __shared__ float sA[64][68];
  __shared__ float sW[64][68];
  const int tid = threadIdx.x;
  const int tc = tid & 15, tl = tid >> 4;
  float acc[4][4] = {};
  for (int db = 0; db < 2; ++db) {
    __syncthreads();
    for (int idx = tid; idx < 64 * 64; idx += 256) {
      const int r = idx >> 6, d = idx & 63;
      sA[r][d] = x[(size_t)(lt * 64 + r) * DD + db * 64 + d];
      sW[r][d] = W[(size_t)(ct * 64 + r) * DD + db * 64 + d];
    }
    __syncthreads();
#pragma unroll 4
    for (int d = 0; d < 64; d += 4) {
      float4 a[4], w[4];
#pragma unroll
      for (int q = 0; q < 4; ++q) a[q] = *(const float4*)&sA[tl * 4 + q][d];
#pragma unroll
      for (int j = 0; j < 4; ++j) w[j] = *(const float4*)&sW[tc + 16 * j][d];
#pragma unroll
      for (int j = 0; j < 4; ++j)
#pragma unroll
        for (int q = 0; q < 4; ++q)
          acc[j][q] += a[q].x * w[j].x + a[q].y * w[j].y + a[q].z * w[j].z + a[q].w * w[j].w;
    }
  }
  float* __restrict__ dst = xz + ((size_t)mb * 256 + ct * 64) * LL + lt * 64;
#pragma unroll
  for (int j = 0; j < 4; ++j) {
    float4 v = make_float4(acc[j][0], acc[j][1], acc[j][2], acc[j][3]);
    *(float4*)&dst[(size_t)(tc + 16 * j) * LL + tl * 4] = v;
  }
}

// ---------------- K2: depthwise 3x3 SAME conv + bias + SiLU ---------------
__global__ __launch_bounds__(256) void k_conv(
    const float* __restrict__ xz, const float* __restrict__ conv_w,
    const float* __restrict__ conv_b, float* __restrict__ xc) {
  const int ht = blockIdx.x, dg = blockIdx.y, mb = blockIdx.z;
  const int m = mb >> 2;
  __shared__ float sIn[8][18][66];
  const float* __restrict__ src = xz + ((size_t)mb * 256 + dg * 8) * LL;
  const int tid = threadIdx.x;
  for (int idx = tid; idx < 8 * 18 * 66; idx += 256) {
    const int dd = idx / (18 * 66);
    const int rem = idx - dd * (18 * 66);
    const int hh = rem / 66, ww = rem - hh * 66;
    const int h = ht * 16 + hh - 1, w = ww - 1;
    float v = 0.f;
    if (h >= 0 && h < 64 && w >= 0 && w < 64) v = src[(size_t)dd * LL + h * 64 + w];
    sIn[dd][hh][ww] = v;
  }
  __syncthreads();
  const int dd = tid & 7, wv = tid >> 3;
  const int dch = dg * 8 + dd;
  float wk[9];
#pragma unroll
  for (int t = 0; t < 9; ++t) wk[t] = conv_w[((size_t)m * DD + dch) * 9 + t];
  const float bias = conv_b[m * DD + dch];
  for (int hh = 0; hh < 16; ++hh) {
#pragma unroll
    for (int wh = 0; wh < 2; ++wh) {
      const int w = wv + wh * 32;
      float s = bias;
#pragma unroll
      for (int kh = 0; kh < 3; ++kh)
#pragma unroll
        for (int kw = 0; kw < 3; ++kw)
          s = fmaf(sIn[dd][hh + kh][w + kw], wk[kh * 3 + kw], s);
      s = silu_(s);
      const int l = (ht * 16 + hh) * 64 + w;
      xc[((size_t)mb * LL + l) * DD + dch] = s;
    }
  }
}

// ---------------- K3: x_proj: xdbl[m][b][k][c=24][l] ----------------------
__global__ __launch_bounds__(256) void k_xproj(
    const float* __restrict__ xc, const float* __restrict__ xproj_w,
    float* __restrict__ xdbl) {
  const int lt = blockIdx.x, k = blockIdx.y, mb = blockIdx.z;
  const int m = mb >> 2;
  __shared__ float sX[64][132];
  __shared__ float sW[24][132];
  const int tid = threadIdx.x;
  const float* __restrict__ src = xc + (size_t)mb * LL * DD;
  for (int idx = tid; idx < 64 * 128; idx += 256) {
    const int l = idx >> 7, d = idx & 127;
    sX[l][d] = src[(size_t)phys_idx(k, lt * 64 + l) * DD + d];
  }
  const float* __restrict__ Wsrc = xproj_w + ((size_t)m * 4 + k) * 24 * DD;
  for (int idx = tid; idx < 24 * 128; idx += 256) sW[idx >> 7][idx & 127] = Wsrc[idx];
  __syncthreads();
  const int l = tid >> 2, cg = tid & 3;
  float acc[6] = {};
#pragma unroll 8
  for (int d = 0; d < 128; d += 4) {
    const float4 xv = *(const float4*)&sX[l][d];
#pragma unroll
    for (int j = 0; j < 6; ++j) {
      const float4 wv = *(const float4*)&sW[cg * 6 + j][d];
      acc[j] += xv.x * wv.x + xv.y * wv.y + xv.z * wv.z + xv.w * wv.w;
    }
  }
  float* __restrict__ dst = xdbl + ((size_t)mb * 4 + k) * 24 * LL + lt * 64 + l;
#pragma unroll
  for (int j = 0; j < 6; ++j) dst[(size_t)(cg * 6 + j) * LL] = acc[j];
}

// ===================== segmented selective scan ===========================
// L=4096 split into 16 segments of 256. dt is computed on the fly from xdbl
// (dts rows) + dt_w/dt_b, eliminating the dtb buffer entirely.
static constexpr int SEG = 16;
static constexpr int SEGL = 256;   // 4 chunks of 64

// ---- pass 1: per-segment local scan (h0=0) -> h_end, P (segments 0..14) --
__global__ __launch_bounds__(128) void k_scan1(
    const float* __restrict__ xc, const float* __restrict__ xdbl,
    const float* __restrict__ dt_w, const float* __restrict__ dt_b,
    const float* __restrict__ Alogs, float* __restrict__ hend,
    float* __restrict__ Pseg) {
  const int gx = blockIdx.x;
  const int dg = gx & 7, seg = gx >> 3;      // seg 0..14
  const int k = blockIdx.y, mb = blockIdx.z;
  const int m = mb >> 2, mbk = mb * 4 + k;
  const int tid = threadIdx.x;
  __shared__ float2 sdx[16][65];   // [d][l] = (dt, x)
  __shared__ float sB[8][65];
  __shared__ float sdts[64][10];   // [l][r]
  const int n = tid & 7, dd = (tid >> 3) & 15;
  const int d = dg * 16 + dd;
  const float a = -__expf(Alogs[((size_t)m * 512 + k * DD + d) * 8 + n]);
  const float aln2 = a * 1.4426950408889634f;
  // dt-compute role: this thread computes dt for channel cd, 8 l's
  const int cd = tid & 15, lq = tid >> 4;
  float wreg[8];
#pragma unroll
  for (int r = 0; r < 8; ++r) wreg[r] = dt_w[(((size_t)mbk) * DD + dg * 16 + cd) * 8 + r];
  const float bw = dt_b[(size_t)mbk * DD + dg * 16 + cd];

  const float* __restrict__ tsrc = xdbl + (size_t)mbk * 24 * LL;
  const float* __restrict__ bsrc = tsrc + 8 * LL;
  const float* __restrict__ xsrc = xc + (size_t)mb * LL * DD + dg * 16;

  float px[8], pb[4], pt[4];
  auto stage_load = [&](int c0) {
    const int gl0 = seg * SEGL + c0 * 64;
#pragma unroll
    for (int j = 0; j < 8; ++j) {
      const int idx = tid + j * 128;
      px[j] = xsrc[(size_t)phys_idx(k, gl0 + (idx >> 4)) * DD + (idx & 15)];
    }
#pragma unroll
    for (int j = 0; j < 4; ++j) {
      const int idx = tid + j * 128;
      const int r = idx >> 6, l = idx & 63;
      pb[j] = bsrc[(size_t)r * LL + gl0 + l];
      pt[j] = tsrc[(size_t)r * LL + gl0 + l];
    }
  };
  auto stage_store = [&]() {
#pragma unroll
    for (int j = 0; j < 8; ++j) {
      const int idx = tid + j * 128;
      sdx[idx & 15][idx >> 4].y = px[j];
    }
#pragma unroll
    for (int j = 0; j < 4; ++j) {
      const int idx = tid + j * 128;
      sB[idx >> 6][idx & 63] = pb[j];
      sdts[idx & 63][idx >> 6] = pt[j];
    }
  };
  auto dt_compute = [&]() {
#pragma unroll
    for (int i = 0; i < 8; ++i) {
      const int l = lq * 8 + i;
      const float2 t0 = *(const float2*)&sdts[l][0];
      const float2 t1 = *(const float2*)&sdts[l][2];
      const float2 t2 = *(const float2*)&sdts[l][4];
      const float2 t3 = *(const float2*)&sdts[l][6];
      float s = bw;
      s = fmaf(t0.x, wreg[0], s); s = fmaf(t0.y, wreg[1], s);
      s = fmaf(t1.x, wreg[2], s); s = fmaf(t1.y, wreg[3], s);
      s = fmaf(t2.x, wreg[4], s); s = fmaf(t2.y, wreg[5], s);
      s = fmaf(t3.x, wreg[6], s); s = fmaf(t3.y, wreg[7], s);
      sdx[cd][l].x = softplus_(s);
    }
  };

  stage_load(0);
  stage_store();
  __syncthreads();
  dt_compute();
  __syncthreads();
  float h = 0.f, dtsum = 0.f;
  for (int c0 = 0; c0 < 4; ++c0) {
    if (c0 < 3) stage_load(c0 + 1);
#pragma unroll 8
    for (int l = 0; l < 64; ++l) {
      const float2 dx = sdx[dd][l];
      const float b = sB[n][l];
      const float e = __builtin_amdgcn_exp2f(dx.x * aln2);
      h = fmaf(h, e, dx.x * dx.y * b);
      dtsum += dx.x;
    }
    if (c0 < 3) {
      __syncthreads();
      stage_store();
      __syncthreads();
      dt_compute();
      __syncthreads();
    }
  }
  const size_t oidx = (((size_t)mbk * SEG + seg) << 10) + (size_t)d * 8 + n;
  hend[oidx] = h;
  Pseg[oidx] = __builtin_amdgcn_exp2f(aln2 * dtsum);
}

// ---- pass 2: sequential combine across segments -> h_in ------------------
__global__ __launch_bounds__(256) void k_scan2(
    const float* __restrict__ hend, const float* __restrict__ Pseg,
    float* __restrict__ hin) {
  const int gid = blockIdx.x * 256 + threadIdx.x;   // 32768
  const int mbk = gid >> 10, dn = gid & 1023;
  float h = 0.f;
  for (int s = 0; s < SEG; ++s) {
    const size_t idx = (((size_t)mbk * SEG + s) << 10) + dn;
    hin[idx] = h;
    if (s < SEG - 1) h = fmaf(Pseg[idx], h, hend[idx]);
  }
}

// ---- pass 3: per-segment scan seeded with h_in, produce y (atomics) ------
__global__ __launch_bounds__(128) void k_scan3(
    const float* __restrict__ xc, const float* __restrict__ xdbl,
    const float* __restrict__ dt_w, const float* __restrict__ dt_b,
    const float* __restrict__ Alogs, const float* __restrict__ Ds,
    const float* __restrict__ hin, float* __restrict__ ysum) {
  const int gx = blockIdx.x;
  const int dg = gx & 7, seg = gx >> 3;      // seg 0..15
  const int k = blockIdx.y, mb = blockIdx.z;
  const int m = mb >> 2, mbk = mb * 4 + k;
  const int tid = threadIdx.x;
  __shared__ float2 sdx[16][65];   // [d][l] = (dt, x)
  __shared__ float2 sbc[8][65];    // [n][l] = (B, C)
  __shared__ float sdts[64][10];
  __shared__ float ybuf[64][17];
  const int n = tid & 7, dd = (tid >> 3) & 15;
  const int d = dg * 16 + dd;
  const float a = -__expf(Alogs[((size_t)m * 512 + k * DD + d) * 8 + n]);
  const float aln2 = a * 1.4426950408889634f;
  const float dsv = Ds[(size_t)m * 512 + k * DD + d];
  const int cd = tid & 15, lq = tid >> 4;
  float wreg[8];
#pragma unroll
  for (int r = 0; r < 8; ++r) wreg[r] = dt_w[(((size_t)mbk) * DD + dg * 16 + cd) * 8 + r];
  const float bw = dt_b[(size_t)mbk * DD + dg * 16 + cd];

  const float* __restrict__ tsrc = xdbl + (size_t)mbk * 24 * LL;
  const float* __restrict__ bcsrc = tsrc + 8 * LL;   // B rows 0..7, C rows 8..15
  const float* __restrict__ xsrc = xc + (size_t)mb * LL * DD + dg * 16;
  float* __restrict__ ydst = ysum + (size_t)mb * LL * DD;

  float px[8], pbc[8], pt[4];
  auto stage_load = [&](int c0) {
    const int gl0 = seg * SEGL + c0 * 64;
#pragma unroll
    for (int j = 0; j < 8; ++j) {
      const int idx = tid + j * 128;
      px[j] = xsrc[(size_t)phys_idx(k, gl0 + (idx >> 4)) * DD + (idx & 15)];
      const int r = idx >> 6, l = idx & 63;
      pbc[j] = bcsrc[(size_t)r * LL + gl0 + l];
    }
#pragma unroll
    for (int j = 0; j < 4; ++j) {
      const int idx = tid + j * 128;
      pt[j] = tsrc[(size_t)(idx >> 6) * LL + gl0 + (idx & 63)];
    }
  };
  auto stage_store = [&]() {
#pragma unroll
    for (int j = 0; j < 8; ++j) {
      const int idx = tid + j * 128;
      sdx[idx & 15][idx >> 4].y = px[j];
      const int r = idx >> 6, l = idx & 63;
      if (r < 8) sbc[r][l].x = pbc[j]; else sbc[r - 8][l].y = pbc[j];
    }
#pragma unroll
    for (int j = 0; j < 4; ++j) {
      const int idx = tid + j * 128;
      sdts[idx & 63][idx >> 6] = pt[j];
    }
  };
  auto dt_compute = [&]() {
#pragma unroll
    for (int i = 0; i < 8; ++i) {
      const int l = lq * 8 + i;
      const float2 t0 = *(const float2*)&sdts[l][0];
      const float2 t1 = *(const float2*)&sdts[l][2];
      const float2 t2 = *(const float2*)&sdts[l][4];
      const float2 t3 = *(const float2*)&sdts[l][6];
      float s = bw;
      s = fmaf(t0.x, wreg[0], s); s = fmaf(t0.y, wreg[1], s);
      s = fmaf(t1.x, wreg[2], s); s = fmaf(t1.y, wreg[3], s);
      s = fmaf(t2.x, wreg[4], s); s = fmaf(t2.y, wreg[5], s);
      s = fmaf(t3.x, wreg[6], s); s = fmaf(t3.y, wreg[7], s);
      sdx[cd][l].x = softplus_(s);
    }
  };

  stage_load(0);
  stage_store();
  __syncthreads();
  dt_compute();
  __syncthreads();
  float h = hin[(((size_t)mbk * SEG + seg) << 10) + (size_t)d * 8 + n];
  for (int c0 = 0; c0 < 4; ++c0) {
    if (c0 < 3) stage_load(c0 + 1);
#pragma unroll 8
    for (int l = 0; l < 64; ++l) {
      const float2 dx = sdx[dd][l];
      const float2 bc = sbc[n][l];
      const float e = __builtin_amdgcn_exp2f(dx.x * aln2);
      h = fmaf(h, e, dx.x * dx.y * bc.x);
      float p = h * bc.y;
      p = dpp_add_<0xB1>(p);   // xor1
      p = dpp_add_<0x4E>(p);   // xor2
      p = dpp_add_<0x141>(p);  // row_half_mirror -> full octet sum
      if (n == 0) ybuf[l][dd] = fmaf(dsv, dx.y, p);
    }
    __syncthreads();
    {
      const int fd = tid & 15, fl = tid >> 4;
      const int gl0 = seg * SEGL + c0 * 64;
#pragma unroll
      for (int j2 = 0; j2 < 8; ++j2) {
        const int l = fl + j2 * 8;
        const int lhw = phys_idx(k, gl0 + l);
        unsafeAtomicAdd(&ydst[(size_t)lhw * DD + dg * 16 + fd], ybuf[l][fd]);
      }
    }
    if (c0 < 3) {
      stage_store();
      __syncthreads();
      dt_compute();
      __syncthreads();
    }
  }
}

// ---------------- K6: LN(y) * silu(z) @ out_w^T -> guided[m][b][l][d] -----
__global__ __launch_bounds__(256) void k_outproj(
    const float* __restrict__ ysum, const float* __restrict__ xz,
    const float* __restrict__ ln_g, const float* __restrict__ ln_b,
    const float* __restrict__ out_w, float* __restrict__ guided) {
  const int lt = blockIdx.x, mb = blockIdx.y;
  const int m = mb >> 2;
  __shared__ float sv[64][132];
  __shared__ float sW[64][68];
  __shared__ float smr[64][2];
  __shared__ float sg[128], sb[128];
  const int tid = threadIdx.x;
  if (tid < 128) { sg[tid] = ln_g[m * DD + tid]; sb[tid] = ln_b[m * DD + tid]; }
  const float* __restrict__ ysrc = ysum + ((size_t)mb * LL + lt * 64) * DD;
  for (int idx = tid; idx < 64 * 128; idx += 256) sv[idx >> 7][idx & 127] = ysrc[idx];
  __syncthreads();
  {
    const int l = tid >> 2, q = tid & 3;
    float s = 0.f, s2 = 0.f;
#pragma unroll
    for (int d0 = 0; d0 < 32; d0 += 4) {
      const float4 v = *(const float4*)&sv[l][q * 32 + d0];
      s += v.x + v.y + v.z + v.w;
      s2 += v.x * v.x + v.y * v.y + v.z * v.z + v.w * v.w;
    }
    s = dpp_add_<0xB1>(s); s = dpp_add_<0x4E>(s);
    s2 = dpp_add_<0xB1>(s2); s2 = dpp_add_<0x4E>(s2);
    if (q == 0) {
      const float mean = s * (1.f / 128.f);
      smr[l][0] = mean;
      smr[l][1] = rsqrtf(fmaf(s2, 1.f / 128.f, -mean * mean) + 1e-5f);
    }
  }
  __syncthreads();
  {
    const int c = tid >> 1, half = tid & 1;
    const float* __restrict__ zsrc = xz + ((size_t)mb * 256 + 128 + c) * LL + lt * 64 + half * 32;
    const float g = sg[c], bb = sb[c];
#pragma unroll
    for (int i = 0; i < 32; i += 4) {
      const float4 z4 = *(const float4*)&zsrc[i];
      const float zz[4] = {z4.x, z4.y, z4.z, z4.w};
#pragma unroll
      for (int t = 0; t < 4; ++t) {
        const int l = half * 32 + i + t;
        const float v = fmaf((sv[l][c] - smr[l][0]) * smr[l][1], g, bb);
        sv[l][c] = v * silu_(zz[t]);
      }
    }
  }
  const int tc = tid & 15, tl = tid >> 4;
  const float* __restrict__ Wp = out_w + (size_t)m * DD * DD;
  float* __restrict__ dst = guided + ((size_t)mb * LL + lt * 64) * DD;
  for (int jb = 0; jb < 2; ++jb) {
    float acc[4][4] = {};
    for (int db = 0; db < 2; ++db) {
      __syncthreads();
      for (int idx = tid; idx < 64 * 64; idx += 256) {
        const int r = idx >> 6, dcol = idx & 63;
        sW[r][dcol] = Wp[(size_t)(jb * 64 + r) * DD + db * 64 + dcol];
      }
      __syncthreads();
#pragma unroll 4
      for (int d0 = 0; d0 < 64; d0 += 4) {
        float4 av[4], wv[4];
#pragma unroll
        for (int q = 0; q < 4; ++q) av[q] = *(const float4*)&sv[tl * 4 + q][db * 64 + d0];
#pragma unroll
        for (int j = 0; j < 4; ++j) wv[j] = *(const float4*)&sW[tc + 16 * j][d0];
#pragma unroll
        for (int j = 0; j < 4; ++j)
#pragma unroll
          for (int q = 0; q < 4; ++q)
            acc[j][q] += av[q].x * wv[j].x + av[q].y * wv[j].y + av[q].z * wv[j].z + av[q].w * wv[j].w;
      }
    }
#pragma unroll
    for (int j = 0; j < 4; ++j)
#pragma unroll
      for (int q = 0; q < 4; ++q)
        dst[(size_t)(tl * 4 + q) * DD + jb * 64 + tc + 16 * j] = acc[j][q];
  }
}

// ---------------- K7: enhance (LN -> GEMM -> +bias -> GELU -> +residual) --
__global__ __launch_bounds__(256) void k_enhance(
    const float* __restrict__ guided, const float* __restrict__ eg,
    const float* __restrict__ ebv, const float* __restrict__ ew,
    const float* __restrict__ ebias, const float* __restrict__ sar,
    const float* __restrict__ opt, float* __restrict__ outp) {
  const int lt = blockIdx.x, ib = blockIdx.y;
  const int i = ib >> 2, b = ib & 3;
  __shared__ float sv[64][132];
  __shared__ float sW[64][68];
  __shared__ float smr[64][2];
  __shared__ float sg[128], sb2[128], sbias[128];
  const int tid = threadIdx.x;
  if (tid < 128) {
    sg[tid] = eg[i * DD + tid];
    sb2[tid] = ebv[i * DD + tid];
    sbias[tid] = ebias[i * DD + tid];
  }
  const float* __restrict__ gsrc = guided + (((size_t)(1 - i) * 4 + b) * LL + lt * 64) * DD;
  for (int idx = tid; idx < 64 * 128; idx += 256) sv[idx >> 7][idx & 127] = gsrc[idx];
  __syncthreads();
  {
    const int l = tid >> 2, q = tid & 3;
    float s = 0.f, s2 = 0.f;
#pragma unroll
    for (int d0 = 0; d0 < 32; d0 += 4) {
      const float4 v = *(const float4*)&sv[l][q * 32 + d0];
      s += v.x + v.y + v.z + v.w;
      s2 += v.x * v.x + v.y * v.y + v.z * v.z + v.w * v.w;
    }
    s = dpp_add_<0xB1>(s); s = dpp_add_<0x4E>(s);
    s2 = dpp_add_<0xB1>(s2); s2 = dpp_add_<0x4E>(s2);
    if (q == 0) {
      const float mean = s * (1.f / 128.f);
      smr[l][0] = mean;
      smr[l][1] = rsqrtf(fmaf(s2, 1.f / 128.f, -mean * mean) + 1e-5f);
    }
  }
  __syncthreads();
  {
    const int c = tid >> 1, half = tid & 1;
    const float g = sg[c], bb = sb2[c];
#pragma unroll
    for (int i2 = 0; i2 < 32; ++i2) {
      const int l = half * 32 + i2;
      sv[l][c] = fmaf((sv[l][c] - smr[l][0]) * smr[l][1], g, bb);
    }
  }
  const int tc = tid & 15, tl = tid >> 4;
  const float* __restrict__ Wp = ew + (size_t)i * DD * DD;
  const float* __restrict__ resid = (i == 0 ? sar : opt) + ((size_t)b * LL + lt * 64) * DD;
  float* __restrict__ dst = outp + (size_t)i * (4 * LL * DD) + ((size_t)b * LL + lt * 64) * DD;
  for (int jb = 0; jb < 2; ++jb) {
    float acc[4][4] = {};
    for (int db = 0; db < 2; ++db) {
      __syncthreads();
      for (int idx = tid; idx < 64 * 64; idx += 256) {
        const int r = idx >> 6, dcol = idx & 63;
        sW[r][dcol] = Wp[(size_t)(jb * 64 + r) * DD + db * 64 + dcol];
      }
      __syncthreads();
#pragma unroll 4
      for (int d0 = 0; d0 < 64; d0 += 4) {
        float4 av[4], wv[4];
#pragma unroll
        for (int q = 0; q < 4; ++q) av[q] = *(const float4*)&sv[tl * 4 + q][db * 64 + d0];
#pragma unroll
        for (int j = 0; j < 4; ++j) wv[j] = *(const float4*)&sW[tc + 16 * j][d0];
#pragma unroll
        for (int j = 0; j < 4; ++j)
#pragma unroll
          for (int q = 0; q < 4; ++q)
            acc[j][q] += av[q].x * wv[j].x + av[q].y * wv[j].y + av[q].z * wv[j].z + av[q].w * wv[j].w;
      }
    }
#pragma unroll
    for (int j = 0; j < 4; ++j)
#pragma unroll
      for (int q = 0; q < 4; ++q) {
        const int col = jb * 64 + tc + 16 * j;
        const int row = tl * 4 + q;
        const float u = acc[j][q] + sbias[col];
        dst[(size_t)row * DD + col] = resid[(size_t)row * DD + col] + gelu_(u);
      }
  }
}

extern "C" void kernel_launch(void* const* d_in, const int* in_sizes, int n_in,
                              void* d_out, int out_size, void* d_ws, size_t ws_size,
                              hipStream_t stream) {
  (void)in_sizes; (void)n_in; (void)out_size; (void)ws_size;
  const float* sar    = (const float*)d_in[0];
  const float* opt    = (const float*)d_in[1];
  const float* in_w   = (const float*)d_in[2];
  const float* conv_w = (const float*)d_in[3];
  const float* conv_b = (const float*)d_in[4];
  const float* xproj_w= (const float*)d_in[5];
  const float* dt_w   = (const float*)d_in[6];
  const float* dt_b   = (const float*)d_in[7];
  const float* Alogs  = (const float*)d_in[8];
  const float* Ds     = (const float*)d_in[9];
  const float* ln_g   = (const float*)d_in[10];
  const float* ln_b   = (const float*)d_in[11];
  const float* out_w  = (const float*)d_in[12];
  const float* eg     = (const float*)d_in[13];
  const float* eb     = (const float*)d_in[14];
  const float* ew     = (const float*)d_in[15];
  const float* ebias  = (const float*)d_in[16];

  float* ws     = (float*)d_ws;
  float* xz     = ws;                  // 2*4*256*4096   = 8,388,608
  float* xc     = xz + 8388608;        // 2*4*4096*128   = 4,194,304
  float* xdbl   = xc + 4194304;        // 2*4*4*24*4096  = 3,145,728
  float* ysumb  = xdbl + 3145728;      // 2*4*4096*128   = 4,194,304
  float* guided = ysumb + 4194304;     // 2*4*4096*128   = 4,194,304
  float* hend   = guided + 4194304;    // 32*16*1024     = 524,288
  float* Pseg   = hend + 524288;       // 524,288
  float* hin    = Pseg + 524288;       // 524,288
  float* outf   = (float*)d_out;

  hipMemsetAsync(ysumb, 0, (size_t)4194304 * sizeof(float), stream);
  k_inproj <<<dim3(64, 4, 8), 256, 0, stream>>>(sar, opt, in_w, xz);
  k_conv   <<<dim3(4, 16, 8), 256, 0, stream>>>(xz, conv_w, conv_b, xc);
  k_xproj  <<<dim3(64, 4, 8), 256, 0, stream>>>(xc, xproj_w, xdbl);
  k_scan1  <<<dim3(120, 4, 8), 128, 0, stream>>>(xc, xdbl, dt_w, dt_b, Alogs, hend, Pseg);
  k_scan2  <<<dim3(128), 256, 0, stream>>>(hend, Pseg, hin);
  k_scan3  <<<dim3(128, 4, 8), 128, 0, stream>>>(xc, xdbl, dt_w, dt_b, Alogs, Ds, hin, ysumb);
  k_outproj<<<dim3(64, 8), 256, 0, stream>>>(ysumb, xz, ln_g, ln_b, out_w, guided);
  k_enhance<<<dim3(64, 8), 256, 0, stream>>>(guided, eg, eb, ew, ebias, sar, opt, outf);
}

// Round 4
// 333.641 us; speedup vs baseline: 1.7036x; 1.3068x over previous
//
#include <hip/hip_runtime.h>
#include <hip/hip_bf16.h>
#include <math.h>

#define DEV __device__ __forceinline__

static constexpr int LL = 4096;   // H*W
static constexpr int DD = 128;    // hidden
static constexpr int SEG = 64;    // segments per scan
static constexpr float LOG2E = 1.4426950408889634f;
static constexpr float LN2 = 0.6931471805599453f;

DEV float silu_(float x) { return x / (1.f + __expf(-x)); }
DEV float gelu_(float x) { return 0.5f * x * (1.f + erff(x * 0.7071067811865475f)); }
// softplus via exp2/log2 (cheap, robust)
DEV float sp_(float x) {
  const float t = __builtin_amdgcn_exp2f(-fabsf(x) * LOG2E);
  return fmaxf(x, 0.f) + LN2 * __builtin_amdgcn_logf(1.f + t);
}

template <int CTRL>
DEV float dpp_add_(float x) {
  int y = __builtin_amdgcn_update_dpp(0, __float_as_int(x), CTRL, 0xF, 0xF, true);
  return x + __int_as_float(y);
}

// segment s of direction k covers hw positions base + i*step, i=0..63
DEV void seg_base_step(int k, int s, int& base, int& step) {
  if (k == 0)      { base = s * 64;        step = 1;   }
  else if (k == 1) { base = s;             step = 64;  }
  else if (k == 2) { base = 4095 - s * 64; step = -1;  }
  else             { base = 4095 - s;      step = -64; }
}

// ---------------- K1: in_proj: xz[m][b][c][l] = x @ in_w^T (c-major out) ----
__global__ __launch_bounds__(256) void k_inproj(
    const float* __restrict__ sar, const float* __restrict__ opt,
    const float* __restrict__ in_w, float* __restrict__ xz) {
  const int lt = blockIdx.x, ct = blockIdx.y, mb = blockIdx.z;
  const int m = mb >> 2;
  const float* __restrict__ x = (m == 0 ? opt : sar) + (size_t)(mb & 3) * (LL * DD);
  const float* __restrict__ W = in_w + (size_t)m * 256 * DD;
  __shared__ float sA[64][68];
  __shared__ float sW[64][68];
  const int tid = threadIdx.x;
  const int tc = tid & 15, tl = tid >> 4;
  float acc[4][4] = {};
  for (int db = 0; db < 2; ++db) {
    __syncthreads();
    for (int idx = tid; idx < 64 * 64; idx += 256) {
      const int r = idx >> 6, d = idx & 63;
      sA[r][d] = x[(size_t)(lt * 64 + r) * DD + db * 64 + d];
      sW[r][d] = W[(size_t)(ct * 64 + r) * DD + db * 64 + d];
    }
    __syncthreads();
#pragma unroll 4
    for (int d = 0; d < 64; d += 4) {
      float4 a[4], w[4];
#pragma unroll
      for (int q = 0; q < 4; ++q) a[q] = *(const float4*)&sA[tl * 4 + q][d];
#pragma unroll
      for (int j = 0; j < 4; ++j) w[j] = *(const float4*)&sW[tc + 16 * j][d];
#pragma unroll
      for (int j = 0; j < 4; ++j)
#pragma unroll
        for (int q = 0; q < 4; ++q)
          acc[j][q] += a[q].x * w[j].x + a[q].y * w[j].y + a[q].z * w[j].z + a[q].w * w[j].w;
    }
  }
  float* __restrict__ dst = xz + ((size_t)mb * 256 + ct * 64) * LL + lt * 64;
#pragma unroll
  for (int j = 0; j < 4; ++j) {
    float4 v = make_float4(acc[j][0], acc[j][1], acc[j][2], acc[j][3]);
    *(float4*)&dst[(size_t)(tc + 16 * j) * LL + tl * 4] = v;
  }
}

// ---------------- K2: depthwise 3x3 SAME conv + bias + SiLU ---------------
__global__ __launch_bounds__(256) void k_conv(
    const float* __restrict__ xz, const float* __restrict__ conv_w,
    const float* __restrict__ conv_b, float* __restrict__ xc) {
  const int ht = blockIdx.x, dg = blockIdx.y, mb = blockIdx.z;
  const int m = mb >> 2;
  __shared__ float sIn[8][18][66];
  const float* __restrict__ src = xz + ((size_t)mb * 256 + dg * 8) * LL;
  const int tid = threadIdx.x;
  for (int idx = tid; idx < 8 * 18 * 66; idx += 256) {
    const int dd = idx / (18 * 66);
    const int rem = idx - dd * (18 * 66);
    const int hh = rem / 66, ww = rem - hh * 66;
    const int h = ht * 16 + hh - 1, w = ww - 1;
    float v = 0.f;
    if (h >= 0 && h < 64 && w >= 0 && w < 64) v = src[(size_t)dd * LL + h * 64 + w];
    sIn[dd][hh][ww] = v;
  }
  __syncthreads();
  const int dd = tid & 7, wv = tid >> 3;
  const int dch = dg * 8 + dd;
  float wk[9];
#pragma unroll
  for (int t = 0; t < 9; ++t) wk[t] = conv_w[((size_t)m * DD + dch) * 9 + t];
  const float bias = conv_b[m * DD + dch];
  for (int hh = 0; hh < 16; ++hh) {
#pragma unroll
    for (int wh = 0; wh < 2; ++wh) {
      const int w = wv + wh * 32;
      float s = bias;
#pragma unroll
      for (int kh = 0; kh < 3; ++kh)
#pragma unroll
        for (int kw = 0; kw < 3; ++kw)
          s = fmaf(sIn[dd][hh + kh][w + kw], wk[kh * 3 + kw], s);
      s = silu_(s);
      const int l = (ht * 16 + hh) * 64 + w;
      xc[((size_t)mb * LL + l) * DD + dch] = s;
    }
  }
}

// ---------------- K3: x_proj -> xdbl[mbk][l][24]  (l-major, contiguous) ---
__global__ __launch_bounds__(256) void k_xproj(
    const float* __restrict__ xc, const float* __restrict__ xproj_w,
    float* __restrict__ xdbl) {
  const int lt = blockIdx.x, k = blockIdx.y, mb = blockIdx.z;
  const int m = mb >> 2, mbk = mb * 4 + k;
  __shared__ float sX[64][132];
  __shared__ float sW[24][132];
  const int tid = threadIdx.x;
  const float* __restrict__ src = xc + (size_t)mb * LL * DD;
  int base, step;
  seg_base_step(k, lt, base, step);
  for (int idx = tid; idx < 64 * 128; idx += 256) {
    const int l = idx >> 7, d = idx & 127;
    sX[l][d] = src[(size_t)(base + l * step) * DD + d];
  }
  const float* __restrict__ Wsrc = xproj_w + ((size_t)m * 4 + k) * 24 * DD;
  for (int idx = tid; idx < 24 * 128; idx += 256) sW[idx >> 7][idx & 127] = Wsrc[idx];
  __syncthreads();
  const int l = tid >> 2, cg = tid & 3;
  float acc[6] = {};
#pragma unroll 8
  for (int d = 0; d < 128; d += 4) {
    const float4 xv = *(const float4*)&sX[l][d];
#pragma unroll
    for (int j = 0; j < 6; ++j) {
      const float4 wv = *(const float4*)&sW[cg * 6 + j][d];
      acc[j] += xv.x * wv.x + xv.y * wv.y + xv.z * wv.z + xv.w * wv.w;
    }
  }
  float* __restrict__ dst = xdbl + ((size_t)mbk * LL + lt * 64 + l) * 24 + cg * 6;
#pragma unroll
  for (int j = 0; j < 6; ++j) dst[j] = acc[j];
}

// ===================== segmented selective scan ===========================
// Register-state scan: thread = d, 8 n-states in VGPRs. SEGL = 64 (one image
// row/col per segment) so the scan->hw map is linear: pos = base + i*step.

// ---- pass 1: per-segment local scan (h0=0) -> h_end, P (segs 0..62) ------
__global__ __launch_bounds__(128) void k_scan1(
    const float* __restrict__ xc, const float* __restrict__ xdbl,
    const float* __restrict__ dt_w, const float* __restrict__ dt_b,
    const float* __restrict__ Alogs, float* __restrict__ hend,
    float* __restrict__ Pseg) {
  const int seg = blockIdx.x;               // 0..62
  const int k = blockIdx.y, mb = blockIdx.z;
  const int m = mb >> 2, mbk = mb * 4 + k;
  const int d = threadIdx.x;                // 0..127
  __shared__ float slds[64 * 24];

  float aln2[8];
  {
    const float4 a0 = *(const float4*)&Alogs[((size_t)m * 512 + k * DD + d) * 8];
    const float4 a1 = *(const float4*)&Alogs[((size_t)m * 512 + k * DD + d) * 8 + 4];
    aln2[0] = -__expf(a0.x) * LOG2E; aln2[1] = -__expf(a0.y) * LOG2E;
    aln2[2] = -__expf(a0.z) * LOG2E; aln2[3] = -__expf(a0.w) * LOG2E;
    aln2[4] = -__expf(a1.x) * LOG2E; aln2[5] = -__expf(a1.y) * LOG2E;
    aln2[6] = -__expf(a1.z) * LOG2E; aln2[7] = -__expf(a1.w) * LOG2E;
  }
  float wreg[8];
  {
    const float4 w0 = *(const float4*)&dt_w[((size_t)mbk * DD + d) * 8];
    const float4 w1 = *(const float4*)&dt_w[((size_t)mbk * DD + d) * 8 + 4];
    wreg[0] = w0.x; wreg[1] = w0.y; wreg[2] = w0.z; wreg[3] = w0.w;
    wreg[4] = w1.x; wreg[5] = w1.y; wreg[6] = w1.z; wreg[7] = w1.w;
  }
  const float bw = dt_b[(size_t)mbk * DD + d];

  // stage dts/B/C chunk (contiguous 6KB)
  const float* __restrict__ tsrc = xdbl + ((size_t)mbk * LL + seg * 64) * 24;
#pragma unroll
  for (int t = 0; t < 3; ++t) {
    const int idx = d + t * 128;
    ((float4*)slds)[idx] = ((const float4*)tsrc)[idx];
  }

  int base, step;
  seg_base_step(k, seg, base, step);
  const float* __restrict__ xsrc = xc + (size_t)mb * LL * DD + (size_t)base * DD + d;
  const ptrdiff_t sstep = (ptrdiff_t)step * DD;

  float xreg[8];
#pragma unroll
  for (int j = 0; j < 8; ++j) xreg[j] = xsrc[(ptrdiff_t)j * sstep];
  __syncthreads();

  float h[8] = {0.f, 0.f, 0.f, 0.f, 0.f, 0.f, 0.f, 0.f};
  float dtsum = 0.f;
#pragma unroll
  for (int i = 0; i < 64; ++i) {
    const float x = xreg[i & 7];
    if (i + 8 < 64) xreg[i & 7] = xsrc[(ptrdiff_t)(i + 8) * sstep];
    const float4 t0 = *(const float4*)&slds[i * 24 + 0];
    const float4 t1 = *(const float4*)&slds[i * 24 + 4];
    float s = bw;
    s = fmaf(t0.x, wreg[0], s); s = fmaf(t0.y, wreg[1], s);
    s = fmaf(t0.z, wreg[2], s); s = fmaf(t0.w, wreg[3], s);
    s = fmaf(t1.x, wreg[4], s); s = fmaf(t1.y, wreg[5], s);
    s = fmaf(t1.z, wreg[6], s); s = fmaf(t1.w, wreg[7], s);
    const float dt = sp_(s);
    const float u = dt * x;
    dtsum += dt;
    const float4 b0 = *(const float4*)&slds[i * 24 + 8];
    const float4 b1 = *(const float4*)&slds[i * 24 + 12];
    h[0] = fmaf(h[0], __builtin_amdgcn_exp2f(dt * aln2[0]), u * b0.x);
    h[1] = fmaf(h[1], __builtin_amdgcn_exp2f(dt * aln2[1]), u * b0.y);
    h[2] = fmaf(h[2], __builtin_amdgcn_exp2f(dt * aln2[2]), u * b0.z);
    h[3] = fmaf(h[3], __builtin_amdgcn_exp2f(dt * aln2[3]), u * b0.w);
    h[4] = fmaf(h[4], __builtin_amdgcn_exp2f(dt * aln2[4]), u * b1.x);
    h[5] = fmaf(h[5], __builtin_amdgcn_exp2f(dt * aln2[5]), u * b1.y);
    h[6] = fmaf(h[6], __builtin_amdgcn_exp2f(dt * aln2[6]), u * b1.z);
    h[7] = fmaf(h[7], __builtin_amdgcn_exp2f(dt * aln2[7]), u * b1.w);
  }
  float* __restrict__ he = hend + (((size_t)mbk * SEG + seg) << 10) + d * 8;
  float* __restrict__ pe = Pseg + (((size_t)mbk * SEG + seg) << 10) + d * 8;
  *(float4*)&he[0] = make_float4(h[0], h[1], h[2], h[3]);
  *(float4*)&he[4] = make_float4(h[4], h[5], h[6], h[7]);
  *(float4*)&pe[0] = make_float4(
      __builtin_amdgcn_exp2f(aln2[0] * dtsum), __builtin_amdgcn_exp2f(aln2[1] * dtsum),
      __builtin_amdgcn_exp2f(aln2[2] * dtsum), __builtin_amdgcn_exp2f(aln2[3] * dtsum));
  *(float4*)&pe[4] = make_float4(
      __builtin_amdgcn_exp2f(aln2[4] * dtsum), __builtin_amdgcn_exp2f(aln2[5] * dtsum),
      __builtin_amdgcn_exp2f(aln2[6] * dtsum), __builtin_amdgcn_exp2f(aln2[7] * dtsum));
}

// ---- pass 2: sequential combine across segments -> h_in ------------------
__global__ __launch_bounds__(256) void k_scan2(
    const float* __restrict__ hend, const float* __restrict__ Pseg,
    float* __restrict__ hin) {
  const int gid = blockIdx.x * 256 + threadIdx.x;   // 32768
  const int mbk = gid >> 10, dn = gid & 1023;
  const float* __restrict__ P = Pseg + ((size_t)mbk << 16) + dn;
  const float* __restrict__ E = hend + ((size_t)mbk << 16) + dn;
  float* __restrict__ O = hin + ((size_t)mbk << 16) + dn;
  float h = 0.f;
#pragma unroll
  for (int s = 0; s < SEG; ++s) {
    O[(size_t)s << 10] = h;
    if (s < SEG - 1) h = fmaf(P[(size_t)s << 10], h, E[(size_t)s << 10]);
  }
}

// ---- pass 3: per-segment scan seeded with h_in, produce y (atomics) ------
__global__ __launch_bounds__(128) void k_scan3(
    const float* __restrict__ xc, const float* __restrict__ xdbl,
    const float* __restrict__ dt_w, const float* __restrict__ dt_b,
    const float* __restrict__ Alogs, const float* __restrict__ Ds,
    const float* __restrict__ hin, float* __restrict__ ysum) {
  const int seg = blockIdx.x;               // 0..63
  const int k = blockIdx.y, mb = blockIdx.z;
  const int m = mb >> 2, mbk = mb * 4 + k;
  const int d = threadIdx.x;                // 0..127
  __shared__ float slds[64 * 24];

  float aln2[8];
  {
    const float4 a0 = *(const float4*)&Alogs[((size_t)m * 512 + k * DD + d) * 8];
    const float4 a1 = *(const float4*)&Alogs[((size_t)m * 512 + k * DD + d) * 8 + 4];
    aln2[0] = -__expf(a0.x) * LOG2E; aln2[1] = -__expf(a0.y) * LOG2E;
    aln2[2] = -__expf(a0.z) * LOG2E; aln2[3] = -__expf(a0.w) * LOG2E;
    aln2[4] = -__expf(a1.x) * LOG2E; aln2[5] = -__expf(a1.y) * LOG2E;
    aln2[6] = -__expf(a1.z) * LOG2E; aln2[7] = -__expf(a1.w) * LOG2E;
  }
  float wreg[8];
  {
    const float4 w0 = *(const float4*)&dt_w[((size_t)mbk * DD + d) * 8];
    const float4 w1 = *(const float4*)&dt_w[((size_t)mbk * DD + d) * 8 + 4];
    wreg[0] = w0.x; wreg[1] = w0.y; wreg[2] = w0.z; wreg[3] = w0.w;
    wreg[4] = w1.x; wreg[5] = w1.y; wreg[6] = w1.z; wreg[7] = w1.w;
  }
  const float bw = dt_b[(size_t)mbk * DD + d];
  const float dsv = Ds[(size_t)m * 512 + k * DD + d];

  const float* __restrict__ tsrc = xdbl + ((size_t)mbk * LL + seg * 64) * 24;
#pragma unroll
  for (int t = 0; t < 3; ++t) {
    const int idx = d + t * 128;
    ((float4*)slds)[idx] = ((const float4*)tsrc)[idx];
  }

  int base, step;
  seg_base_step(k, seg, base, step);
  const float* __restrict__ xsrc = xc + (size_t)mb * LL * DD + (size_t)base * DD + d;
  float* __restrict__ ydst = ysum + (size_t)mb * LL * DD + (size_t)base * DD + d;
  const ptrdiff_t sstep = (ptrdiff_t)step * DD;

  float xreg[8];
#pragma unroll
  for (int j = 0; j < 8; ++j) xreg[j] = xsrc[(ptrdiff_t)j * sstep];

  float h[8];
  {
    const float* __restrict__ hp = hin + (((size_t)mbk * SEG + seg) << 10) + d * 8;
    const float4 h0 = *(const float4*)&hp[0];
    const float4 h1 = *(const float4*)&hp[4];
    h[0] = h0.x; h[1] = h0.y; h[2] = h0.z; h[3] = h0.w;
    h[4] = h1.x; h[5] = h1.y; h[6] = h1.z; h[7] = h1.w;
  }
  __syncthreads();

#pragma unroll
  for (int i = 0; i < 64; ++i) {
    const float x = xreg[i & 7];
    if (i + 8 < 64) xreg[i & 7] = xsrc[(ptrdiff_t)(i + 8) * sstep];
    const float4 t0 = *(const float4*)&slds[i * 24 + 0];
    const float4 t1 = *(const float4*)&slds[i * 24 + 4];
    float s = bw;
    s = fmaf(t0.x, wreg[0], s); s = fmaf(t0.y, wreg[1], s);
    s = fmaf(t0.z, wreg[2], s); s = fmaf(t0.w, wreg[3], s);
    s = fmaf(t1.x, wreg[4], s); s = fmaf(t1.y, wreg[5], s);
    s = fmaf(t1.z, wreg[6], s); s = fmaf(t1.w, wreg[7], s);
    const float dt = sp_(s);
    const float u = dt * x;
    const float4 b0 = *(const float4*)&slds[i * 24 + 8];
    const float4 b1 = *(const float4*)&slds[i * 24 + 12];
    const float4 c0 = *(const float4*)&slds[i * 24 + 16];
    const float4 c1 = *(const float4*)&slds[i * 24 + 20];
    float y = dsv * x;
    h[0] = fmaf(h[0], __builtin_amdgcn_exp2f(dt * aln2[0]), u * b0.x); y = fmaf(h[0], c0.x, y);
    h[1] = fmaf(h[1], __builtin_amdgcn_exp2f(dt * aln2[1]), u * b0.y); y = fmaf(h[1], c0.y, y);
    h[2] = fmaf(h[2], __builtin_amdgcn_exp2f(dt * aln2[2]), u * b0.z); y = fmaf(h[2], c0.z, y);
    h[3] = fmaf(h[3], __builtin_amdgcn_exp2f(dt * aln2[3]), u * b0.w); y = fmaf(h[3], c0.w, y);
    h[4] = fmaf(h[4], __builtin_amdgcn_exp2f(dt * aln2[4]), u * b1.x); y = fmaf(h[4], c1.x, y);
    h[5] = fmaf(h[5], __builtin_amdgcn_exp2f(dt * aln2[5]), u * b1.y); y = fmaf(h[5], c1.y, y);
    h[6] = fmaf(h[6], __builtin_amdgcn_exp2f(dt * aln2[6]), u * b1.z); y = fmaf(h[6], c1.z, y);
    h[7] = fmaf(h[7], __builtin_amdgcn_exp2f(dt * aln2[7]), u * b1.w); y = fmaf(h[7], c1.w, y);
    unsafeAtomicAdd(ydst + (ptrdiff_t)i * sstep, y);
  }
}

// ---------------- K6: LN(y) * silu(z) @ out_w^T -> guided[m][b][l][d] -----
__global__ __launch_bounds__(256) void k_outproj(
    const float* __restrict__ ysum, const float* __restrict__ xz,
    const float* __restrict__ ln_g, const float* __restrict__ ln_b,
    const float* __restrict__ out_w, float* __restrict__ guided) {
  const int lt = blockIdx.x, mb = blockIdx.y;
  const int m = mb >> 2;
  __shared__ float sv[64][132];
  __shared__ float sW[64][68];
  __shared__ float smr[64][2];
  __shared__ float sg[128], sb[128];
  const int tid = threadIdx.x;
  if (tid < 128) { sg[tid] = ln_g[m * DD + tid]; sb[tid] = ln_b[m * DD + tid]; }
  const float* __restrict__ ysrc = ysum + ((size_t)mb * LL + lt * 64) * DD;
  for (int idx = tid; idx < 64 * 128; idx += 256) sv[idx >> 7][idx & 127] = ysrc[idx];
  __syncthreads();
  {
    const int l = tid >> 2, q = tid & 3;
    float s = 0.f, s2 = 0.f;
#pragma unroll
    for (int d0 = 0; d0 < 32; d0 += 4) {
      const float4 v = *(const float4*)&sv[l][q * 32 + d0];
      s += v.x + v.y + v.z + v.w;
      s2 += v.x * v.x + v.y * v.y + v.z * v.z + v.w * v.w;
    }
    s = dpp_add_<0xB1>(s); s = dpp_add_<0x4E>(s);
    s2 = dpp_add_<0xB1>(s2); s2 = dpp_add_<0x4E>(s2);
    if (q == 0) {
      const float mean = s * (1.f / 128.f);
      smr[l][0] = mean;
      smr[l][1] = rsqrtf(fmaf(s2, 1.f / 128.f, -mean * mean) + 1e-5f);
    }
  }
  __syncthreads();
  {
    const int c = tid >> 1, half = tid & 1;
    const float* __restrict__ zsrc = xz + ((size_t)mb * 256 + 128 + c) * LL + lt * 64 + half * 32;
    const float g = sg[c], bb = sb[c];
#pragma unroll
    for (int i = 0; i < 32; i += 4) {
      const float4 z4 = *(const float4*)&zsrc[i];
      const float zz[4] = {z4.x, z4.y, z4.z, z4.w};
#pragma unroll
      for (int t = 0; t < 4; ++t) {
        const int l = half * 32 + i + t;
        const float v = fmaf((sv[l][c] - smr[l][0]) * smr[l][1], g, bb);
        sv[l][c] = v * silu_(zz[t]);
      }
    }
  }
  const int tc = tid & 15, tl = tid >> 4;
  const float* __restrict__ Wp = out_w + (size_t)m * DD * DD;
  float* __restrict__ dst = guided + ((size_t)mb * LL + lt * 64) * DD;
  for (int jb = 0; jb < 2; ++jb) {
    float acc[4][4] = {};
    for (int db = 0; db < 2; ++db) {
      __syncthreads();
      for (int idx = tid; idx < 64 * 64; idx += 256) {
        const int r = idx >> 6, dcol = idx & 63;
        sW[r][dcol] = Wp[(size_t)(jb * 64 + r) * DD + db * 64 + dcol];
      }
      __syncthreads();
#pragma unroll 4
      for (int d0 = 0; d0 < 64; d0 += 4) {
        float4 av[4], wv[4];
#pragma unroll
        for (int q = 0; q < 4; ++q) av[q] = *(const float4*)&sv[tl * 4 + q][db * 64 + d0];
#pragma unroll
        for (int j = 0; j < 4; ++j) wv[j] = *(const float4*)&sW[tc + 16 * j][d0];
#pragma unroll
        for (int j = 0; j < 4; ++j)
#pragma unroll
          for (int q = 0; q < 4; ++q)
            acc[j][q] += av[q].x * wv[j].x + av[q].y * wv[j].y + av[q].z * wv[j].z + av[q].w * wv[j].w;
      }
    }
#pragma unroll
    for (int j = 0; j < 4; ++j)
#pragma unroll
      for (int q = 0; q < 4; ++q)
        dst[(size_t)(tl * 4 + q) * DD + jb * 64 + tc + 16 * j] = acc[j][q];
  }
}

// ---------------- K7: enhance (LN -> GEMM -> +bias -> GELU -> +residual) --
__global__ __launch_bounds__(256) void k_enhance(
    const float* __restrict__ guided, const float* __restrict__ eg,
    const float* __restrict__ ebv, const float* __restrict__ ew,
    const float* __restrict__ ebias, const float* __restrict__ sar,
    const float* __restrict__ opt, float* __restrict__ outp) {
  const int lt = blockIdx.x, ib = blockIdx.y;
  const int i = ib >> 2, b = ib & 3;
  __shared__ float sv[64][132];
  __shared__ float sW[64][68];
  __shared__ float smr[64][2];
  __shared__ float sg[128], sb2[128], sbias[128];
  const int tid = threadIdx.x;
  if (tid < 128) {
    sg[tid] = eg[i * DD + tid];
    sb2[tid] = ebv[i * DD + tid];
    sbias[tid] = ebias[i * DD + tid];
  }
  const float* __restrict__ gsrc = guided + (((size_t)(1 - i) * 4 + b) * LL + lt * 64) * DD;
  for (int idx = tid; idx < 64 * 128; idx += 256) sv[idx >> 7][idx & 127] = gsrc[idx];
  __syncthreads();
  {
    const int l = tid >> 2, q = tid & 3;
    float s = 0.f, s2 = 0.f;
#pragma unroll
    for (int d0 = 0; d0 < 32; d0 += 4) {
      const float4 v = *(const float4*)&sv[l][q * 32 + d0];
      s += v.x + v.y + v.z + v.w;
      s2 += v.x * v.x + v.y * v.y + v.z * v.z + v.w * v.w;
    }
    s = dpp_add_<0xB1>(s); s = dpp_add_<0x4E>(s);
    s2 = dpp_add_<0xB1>(s2); s2 = dpp_add_<0x4E>(s2);
    if (q == 0) {
      const float mean = s * (1.f / 128.f);
      smr[l][0] = mean;
      smr[l][1] = rsqrtf(fmaf(s2, 1.f / 128.f, -mean * mean) + 1e-5f);
    }
  }
  __syncthreads();
  {
    const int c = tid >> 1, half = tid & 1;
    const float g = sg[c], bb = sb2[c];
#pragma unroll
    for (int i2 = 0; i2 < 32; ++i2) {
      const int l = half * 32 + i2;
      sv[l][c] = fmaf((sv[l][c] - smr[l][0]) * smr[l][1], g, bb);
    }
  }
  const int tc = tid & 15, tl = tid >> 4;
  const float* __restrict__ Wp = ew + (size_t)i * DD * DD;
  const float* __restrict__ resid = (i == 0 ? sar : opt) + ((size_t)b * LL + lt * 64) * DD;
  float* __restrict__ dst = outp + (size_t)i * (4 * LL * DD) + ((size_t)b * LL + lt * 64) * DD;
  for (int jb = 0; jb < 2; ++jb) {
    float acc[4][4] = {};
    for (int db = 0; db < 2; ++db) {
      __syncthreads();
      for (int idx = tid; idx < 64 * 64; idx += 256) {
        const int r = idx >> 6, dcol = idx & 63;
        sW[r][dcol] = Wp[(size_t)(jb * 64 + r) * DD + db * 64 + dcol];
      }
      __syncthreads();
#pragma unroll 4
      for (int d0 = 0; d0 < 64; d0 += 4) {
        float4 av[4], wv[4];
#pragma unroll
        for (int q = 0; q < 4; ++q) av[q] = *(const float4*)&sv[tl * 4 + q][db * 64 + d0];
#pragma unroll
        for (int j = 0; j < 4; ++j) wv[j] = *(const float4*)&sW[tc + 16 * j][d0];
#pragma unroll
        for (int j = 0; j < 4; ++j)
#pragma unroll
          for (int q = 0; q < 4; ++q)
            acc[j][q] += av[q].x * wv[j].x + av[q].y * wv[j].y + av[q].z * wv[j].z + av[q].w * wv[j].w;
      }
    }
#pragma unroll
    for (int j = 0; j < 4; ++j)
#pragma unroll
      for (int q = 0; q < 4; ++q) {
        const int col = jb * 64 + tc + 16 * j;
        const int row = tl * 4 + q;
        const float u = acc[j][q] + sbias[col];
        dst[(size_t)row * DD + col] = resid[(size_t)row * DD + col] + gelu_(u);
      }
  }
}

extern "C" void kernel_launch(void* const* d_in, const int* in_sizes, int n_in,
                              void* d_out, int out_size, void* d_ws, size_t ws_size,
                              hipStream_t stream) {
  (void)in_sizes; (void)n_in; (void)out_size; (void)ws_size;
  const float* sar    = (const float*)d_in[0];
  const float* opt    = (const float*)d_in[1];
  const float* in_w   = (const float*)d_in[2];
  const float* conv_w = (const float*)d_in[3];
  const float* conv_b = (const float*)d_in[4];
  const float* xproj_w= (const float*)d_in[5];
  const float* dt_w   = (const float*)d_in[6];
  const float* dt_b   = (const float*)d_in[7];
  const float* Alogs  = (const float*)d_in[8];
  const float* Ds     = (const float*)d_in[9];
  const float* ln_g   = (const float*)d_in[10];
  const float* ln_b   = (const float*)d_in[11];
  const float* out_w  = (const float*)d_in[12];
  const float* eg     = (const float*)d_in[13];
  const float* eb     = (const float*)d_in[14];
  const float* ew     = (const float*)d_in[15];
  const float* ebias  = (const float*)d_in[16];

  float* ws     = (float*)d_ws;
  float* xz     = ws;                  // 2*4*256*4096      = 8,388,608
  float* xc     = xz + 8388608;        // 2*4*4096*128      = 4,194,304
  float* xdbl   = xc + 4194304;        // 32*4096*24        = 3,145,728
  float* ysumb  = xdbl + 3145728;      // 2*4*4096*128      = 4,194,304
  float* guided = ysumb + 4194304;     // 2*4*4096*128      = 4,194,304
  float* hend   = guided + 4194304;    // 32*64*1024        = 2,097,152
  float* Pseg   = hend + 2097152;      // 2,097,152
  float* hin    = Pseg + 2097152;      // 2,097,152
  float* outf   = (float*)d_out;

  hipMemsetAsync(ysumb, 0, (size_t)4194304 * sizeof(float), stream);
  k_inproj <<<dim3(64, 4, 8), 256, 0, stream>>>(sar, opt, in_w, xz);
  k_conv   <<<dim3(4, 16, 8), 256, 0, stream>>>(xz, conv_w, conv_b, xc);
  k_xproj  <<<dim3(64, 4, 8), 256, 0, stream>>>(xc, xproj_w, xdbl);
  k_scan1  <<<dim3(63, 4, 8), 128, 0, stream>>>(xc, xdbl, dt_w, dt_b, Alogs, hend, Pseg);
  k_scan2  <<<dim3(128), 256, 0, stream>>>(hend, Pseg, hin);
  k_scan3  <<<dim3(64, 4, 8), 128, 0, stream>>>(xc, xdbl, dt_w, dt_b, Alogs, Ds, hin, ysumb);
  k_outproj<<<dim3(64, 8), 256, 0, stream>>>(ysumb, xz, ln_g, ln_b, out_w, guided);
  k_enhance<<<dim3(64, 8), 256, 0, stream>>>(guided, eg, eb, ew, ebias, sar, opt, outf);
}

// Round 5
// 290.220 us; speedup vs baseline: 1.9585x; 1.1496x over previous
//
#include <hip/hip_runtime.h>
#include <hip/hip_bf16.h>
#include <math.h>

#define DEV __device__ __forceinline__

static constexpr int LL = 4096;   // H*W
static constexpr int DD = 128;    // hidden
static constexpr int SEG = 64;    // segments per scan
static constexpr float LOG2E = 1.4426950408889634f;
static constexpr float LN2 = 0.6931471805599453f;

template <bool B> struct BoolT { static constexpr bool value = B; };

DEV float silu_(float x) { return x / (1.f + __expf(-x)); }
DEV float gelu_(float x) { return 0.5f * x * (1.f + erff(x * 0.7071067811865475f)); }
DEV float sp_(float x) {
  const float t = __builtin_amdgcn_exp2f(-fabsf(x) * LOG2E);
  return fmaxf(x, 0.f) + LN2 * __builtin_amdgcn_logf(1.f + t);
}

template <int CTRL>
DEV float dpp_add_(float x) {
  int y = __builtin_amdgcn_update_dpp(0, __float_as_int(x), CTRL, 0xF, 0xF, true);
  return x + __int_as_float(y);
}

// segment s of direction k covers hw positions base + i*step, i=0..63
DEV void seg_base_step(int k, int s, int& base, int& step) {
  if (k == 0)      { base = s * 64;        step = 1;   }
  else if (k == 1) { base = s;             step = 64;  }
  else if (k == 2) { base = 4095 - s * 64; step = -1;  }
  else             { base = 4095 - s;      step = -64; }
}

// ---------------- K1: in_proj: xz[m][b][c][l] = x @ in_w^T (c-major out) ----
__global__ __launch_bounds__(256) void k_inproj(
    const float* __restrict__ sar, const float* __restrict__ opt,
    const float* __restrict__ in_w, float* __restrict__ xz) {
  const int lt = blockIdx.x, ct = blockIdx.y, mb = blockIdx.z;
  const int m = mb >> 2;
  const float* __restrict__ x = (m == 0 ? opt : sar) + (size_t)(mb & 3) * (LL * DD);
  const float* __restrict__ W = in_w + (size_t)m * 256 * DD;
  __shared__ float sA[64][68];
  __shared__ float sW[64][68];
  const int tid = threadIdx.x;
  const int tc = tid & 15, tl = tid >> 4;
  float acc[4][4] = {};
  for (int db = 0; db < 2; ++db) {
    __syncthreads();
    for (int idx = tid; idx < 64 * 16; idx += 256) {
      const int r = idx >> 4, d4 = (idx & 15) << 2;
      *(float4*)&sA[r][d4] = *(const float4*)&x[(size_t)(lt * 64 + r) * DD + db * 64 + d4];
      *(float4*)&sW[r][d4] = *(const float4*)&W[(size_t)(ct * 64 + r) * DD + db * 64 + d4];
    }
    __syncthreads();
#pragma unroll 4
    for (int d = 0; d < 64; d += 4) {
      float4 a[4], w[4];
#pragma unroll
      for (int q = 0; q < 4; ++q) a[q] = *(const float4*)&sA[tl * 4 + q][d];
#pragma unroll
      for (int j = 0; j < 4; ++j) w[j] = *(const float4*)&sW[tc + 16 * j][d];
#pragma unroll
      for (int j = 0; j < 4; ++j)
#pragma unroll
        for (int q = 0; q < 4; ++q)
          acc[j][q] += a[q].x * w[j].x + a[q].y * w[j].y + a[q].z * w[j].z + a[q].w * w[j].w;
    }
  }
  float* __restrict__ dst = xz + ((size_t)mb * 256 + ct * 64) * LL + lt * 64;
#pragma unroll
  for (int j = 0; j < 4; ++j) {
    float4 v = make_float4(acc[j][0], acc[j][1], acc[j][2], acc[j][3]);
    *(float4*)&dst[(size_t)(tc + 16 * j) * LL + tl * 4] = v;
  }
}

// ---------------- K2: depthwise 3x3 SAME conv + bias + SiLU ---------------
__global__ __launch_bounds__(256) void k_conv(
    const float* __restrict__ xz, const float* __restrict__ conv_w,
    const float* __restrict__ conv_b, float* __restrict__ xc) {
  const int ht = blockIdx.x, dg = blockIdx.y, mb = blockIdx.z;
  const int m = mb >> 2;
  __shared__ float sIn[8][18][66];
  __shared__ float sOut[1024][8];
  const float* __restrict__ src = xz + ((size_t)mb * 256 + dg * 8) * LL;
  const int tid = threadIdx.x;
  for (int idx = tid; idx < 8 * 18 * 66; idx += 256) {
    const int dd = idx / (18 * 66);
    const int rem = idx - dd * (18 * 66);
    const int hh = rem / 66, ww = rem - hh * 66;
    const int h = ht * 16 + hh - 1, w = ww - 1;
    float v = 0.f;
    if (h >= 0 && h < 64 && w >= 0 && w < 64) v = src[(size_t)dd * LL + h * 64 + w];
    sIn[dd][hh][ww] = v;
  }
  __syncthreads();
  const int dd = tid & 7, wv = tid >> 3;
  const int dch = dg * 8 + dd;
  float wk[9];
#pragma unroll
  for (int t = 0; t < 9; ++t) wk[t] = conv_w[((size_t)m * DD + dch) * 9 + t];
  const float bias = conv_b[m * DD + dch];
  for (int hh = 0; hh < 16; ++hh) {
#pragma unroll
    for (int wh = 0; wh < 2; ++wh) {
      const int w = wv + wh * 32;
      float s = bias;
#pragma unroll
      for (int kh = 0; kh < 3; ++kh)
#pragma unroll
        for (int kw = 0; kw < 3; ++kw)
          s = fmaf(sIn[dd][hh + kh][w + kw], wk[kh * 3 + kw], s);
      sOut[hh * 64 + w][dd] = silu_(s);
    }
  }
  __syncthreads();
  float* __restrict__ dst = xc + (size_t)mb * LL * DD + dg * 8;
#pragma unroll
  for (int r = 0; r < 4; ++r) {
    const int pos = tid + r * 256;
    const int l = ht * 1024 + pos;
    *(float4*)&dst[(size_t)l * DD + 0] = *(const float4*)&sOut[pos][0];
    *(float4*)&dst[(size_t)l * DD + 4] = *(const float4*)&sOut[pos][4];
  }
}

// ---------------- K3: x_proj -> xdbl[mbk][l][24]  (l-major, contiguous) ---
__global__ __launch_bounds__(256) void k_xproj(
    const float* __restrict__ xc, const float* __restrict__ xproj_w,
    float* __restrict__ xdbl) {
  const int lt = blockIdx.x, k = blockIdx.y, mb = blockIdx.z;
  const int m = mb >> 2, mbk = mb * 4 + k;
  __shared__ float sX[64][132];
  __shared__ float sW[24][132];
  const int tid = threadIdx.x;
  const float* __restrict__ src = xc + (size_t)mb * LL * DD;
  int base, step;
  seg_base_step(k, lt, base, step);
  for (int idx = tid; idx < 64 * 32; idx += 256) {
    const int l = idx >> 5, d4 = (idx & 31) << 2;
    *(float4*)&sX[l][d4] = *(const float4*)&src[(size_t)(base + l * step) * DD + d4];
  }
  const float* __restrict__ Wsrc = xproj_w + ((size_t)m * 4 + k) * 24 * DD;
  for (int idx = tid; idx < 24 * 32; idx += 256) {
    const int r = idx >> 5, d4 = (idx & 31) << 2;
    *(float4*)&sW[r][d4] = *(const float4*)&Wsrc[(size_t)r * DD + d4];
  }
  __syncthreads();
  const int l = tid >> 2, cg = tid & 3;
  float acc[6] = {};
#pragma unroll 8
  for (int d = 0; d < 128; d += 4) {
    const float4 xv = *(const float4*)&sX[l][d];
#pragma unroll
    for (int j = 0; j < 6; ++j) {
      const float4 wv = *(const float4*)&sW[cg * 6 + j][d];
      acc[j] += xv.x * wv.x + xv.y * wv.y + xv.z * wv.z + xv.w * wv.w;
    }
  }
  float* __restrict__ dst = xdbl + ((size_t)mbk * LL + lt * 64 + l) * 24 + cg * 6;
#pragma unroll
  for (int j = 0; j < 6; ++j) dst[j] = acc[j];
}

// ===================== segmented selective scan ===========================
// Register-state scan: thread = d, 8 n-states in VGPRs. SEGL = 64.
// Fast path: if aln2[n] == (n+1)*aln2[0] (true for A_logs = log(1..8)),
// all 8 decay factors come from ONE exp2 via a log-depth product chain.

// ---- pass 1: per-segment local scan (h0=0) -> h_end, P (segs 0..62) ------
__global__ __launch_bounds__(128) void k_scan1(
    const float* __restrict__ xc, const float* __restrict__ xdbl,
    const float* __restrict__ dt_w, const float* __restrict__ dt_b,
    const float* __restrict__ Alogs, float* __restrict__ hend,
    float* __restrict__ Pseg) {
  const int seg = blockIdx.x;               // 0..62
  const int k = blockIdx.y, mb = blockIdx.z;
  const int m = mb >> 2, mbk = mb * 4 + k;
  const int d = threadIdx.x;                // 0..127
  __shared__ float slds[64 * 24];

  float aln2[8];
  {
    const float4 a0 = *(const float4*)&Alogs[((size_t)m * 512 + k * DD + d) * 8];
    const float4 a1 = *(const float4*)&Alogs[((size_t)m * 512 + k * DD + d) * 8 + 4];
    aln2[0] = -__expf(a0.x) * LOG2E; aln2[1] = -__expf(a0.y) * LOG2E;
    aln2[2] = -__expf(a0.z) * LOG2E; aln2[3] = -__expf(a0.w) * LOG2E;
    aln2[4] = -__expf(a1.x) * LOG2E; aln2[5] = -__expf(a1.y) * LOG2E;
    aln2[6] = -__expf(a1.z) * LOG2E; aln2[7] = -__expf(a1.w) * LOG2E;
  }
  bool fastp = true;
#pragma unroll
  for (int n = 1; n < 8; ++n)
    fastp = fastp && (fabsf(aln2[n] - (float)(n + 1) * aln2[0]) <=
                      1e-4f * fabsf(aln2[n]) + 1e-12f);
  float wreg[8];
  {
    const float4 w0 = *(const float4*)&dt_w[((size_t)mbk * DD + d) * 8];
    const float4 w1 = *(const float4*)&dt_w[((size_t)mbk * DD + d) * 8 + 4];
    wreg[0] = w0.x; wreg[1] = w0.y; wreg[2] = w0.z; wreg[3] = w0.w;
    wreg[4] = w1.x; wreg[5] = w1.y; wreg[6] = w1.z; wreg[7] = w1.w;
  }
  const float bw = dt_b[(size_t)mbk * DD + d];

  const float* __restrict__ tsrc = xdbl + ((size_t)mbk * LL + seg * 64) * 24;
#pragma unroll
  for (int t = 0; t < 3; ++t) {
    const int idx = d + t * 128;
    ((float4*)slds)[idx] = ((const float4*)tsrc)[idx];
  }

  int base, step;
  seg_base_step(k, seg, base, step);
  const float* __restrict__ xsrc = xc + (size_t)mb * LL * DD + (size_t)base * DD + d;
  const ptrdiff_t sstep = (ptrdiff_t)step * DD;

  float xreg[8];
#pragma unroll
  for (int j = 0; j < 8; ++j) xreg[j] = xsrc[(ptrdiff_t)j * sstep];
  __syncthreads();

  float h[8] = {0.f, 0.f, 0.f, 0.f, 0.f, 0.f, 0.f, 0.f};
  float dtsum = 0.f;

  auto body = [&](auto ft) {
    constexpr bool F = decltype(ft)::value;
#pragma unroll
    for (int i = 0; i < 64; ++i) {
      const float x = xreg[i & 7];
      if (i + 8 < 64) xreg[i & 7] = xsrc[(ptrdiff_t)(i + 8) * sstep];
      const float4 t0 = *(const float4*)&slds[i * 24 + 0];
      const float4 t1 = *(const float4*)&slds[i * 24 + 4];
      float s = bw;
      s = fmaf(t0.x, wreg[0], s); s = fmaf(t0.y, wreg[1], s);
      s = fmaf(t0.z, wreg[2], s); s = fmaf(t0.w, wreg[3], s);
      s = fmaf(t1.x, wreg[4], s); s = fmaf(t1.y, wreg[5], s);
      s = fmaf(t1.z, wreg[6], s); s = fmaf(t1.w, wreg[7], s);
      const float dt = sp_(s);
      const float u = dt * x;
      dtsum += dt;
      float q1, q2, q3, q4, q5, q6, q7, q8;
      if constexpr (F) {
        q1 = __builtin_amdgcn_exp2f(dt * aln2[0]);
        q2 = q1 * q1; q3 = q2 * q1; q4 = q2 * q2;
        q5 = q4 * q1; q6 = q4 * q2; q7 = q4 * q3; q8 = q4 * q4;
      } else {
        q1 = __builtin_amdgcn_exp2f(dt * aln2[0]);
        q2 = __builtin_amdgcn_exp2f(dt * aln2[1]);
        q3 = __builtin_amdgcn_exp2f(dt * aln2[2]);
        q4 = __builtin_amdgcn_exp2f(dt * aln2[3]);
        q5 = __builtin_amdgcn_exp2f(dt * aln2[4]);
        q6 = __builtin_amdgcn_exp2f(dt * aln2[5]);
        q7 = __builtin_amdgcn_exp2f(dt * aln2[6]);
        q8 = __builtin_amdgcn_exp2f(dt * aln2[7]);
      }
      const float4 b0 = *(const float4*)&slds[i * 24 + 8];
      const float4 b1 = *(const float4*)&slds[i * 24 + 12];
      h[0] = fmaf(h[0], q1, u * b0.x);
      h[1] = fmaf(h[1], q2, u * b0.y);
      h[2] = fmaf(h[2], q3, u * b0.z);
      h[3] = fmaf(h[3], q4, u * b0.w);
      h[4] = fmaf(h[4], q5, u * b1.x);
      h[5] = fmaf(h[5], q6, u * b1.y);
      h[6] = fmaf(h[6], q7, u * b1.z);
      h[7] = fmaf(h[7], q8, u * b1.w);
    }
  };
  if (fastp) body(BoolT<true>{}); else body(BoolT<false>{});

  float* __restrict__ he = hend + (((size_t)mbk * SEG + seg) << 10) + d * 8;
  float* __restrict__ pe = Pseg + (((size_t)mbk * SEG + seg) << 10) + d * 8;
  *(float4*)&he[0] = make_float4(h[0], h[1], h[2], h[3]);
  *(float4*)&he[4] = make_float4(h[4], h[5], h[6], h[7]);
  *(float4*)&pe[0] = make_float4(
      __builtin_amdgcn_exp2f(aln2[0] * dtsum), __builtin_amdgcn_exp2f(aln2[1] * dtsum),
      __builtin_amdgcn_exp2f(aln2[2] * dtsum), __builtin_amdgcn_exp2f(aln2[3] * dtsum));
  *(float4*)&pe[4] = make_float4(
      __builtin_amdgcn_exp2f(aln2[4] * dtsum), __builtin_amdgcn_exp2f(aln2[5] * dtsum),
      __builtin_amdgcn_exp2f(aln2[6] * dtsum), __builtin_amdgcn_exp2f(aln2[7] * dtsum));
}

// ---- pass 2: sequential combine across segments -> h_in ------------------
__global__ __launch_bounds__(256) void k_scan2(
    const float* __restrict__ hend, const float* __restrict__ Pseg,
    float* __restrict__ hin) {
  const int gid = blockIdx.x * 256 + threadIdx.x;   // 32768
  const int mbk = gid >> 10, dn = gid & 1023;
  const float* __restrict__ P = Pseg + ((size_t)mbk << 16) + dn;
  const float* __restrict__ E = hend + ((size_t)mbk << 16) + dn;
  float* __restrict__ O = hin + ((size_t)mbk << 16) + dn;
  float h = 0.f;
#pragma unroll
  for (int s = 0; s < SEG; ++s) {
    O[(size_t)s << 10] = h;
    if (s < SEG - 1) h = fmaf(P[(size_t)s << 10], h, E[(size_t)s << 10]);
  }
}

// ---- pass 3: per-segment scan seeded with h_in, produce y (atomics) ------
__global__ __launch_bounds__(128) void k_scan3(
    const float* __restrict__ xc, const float* __restrict__ xdbl,
    const float* __restrict__ dt_w, const float* __restrict__ dt_b,
    const float* __restrict__ Alogs, const float* __restrict__ Ds,
    const float* __restrict__ hin, float* __restrict__ ysum) {
  const int seg = blockIdx.x;               // 0..63
  const int k = blockIdx.y, mb = blockIdx.z;
  const int m = mb >> 2, mbk = mb * 4 + k;
  const int d = threadIdx.x;                // 0..127
  __shared__ float slds[64 * 24];

  float aln2[8];
  {
    const float4 a0 = *(const float4*)&Alogs[((size_t)m * 512 + k * DD + d) * 8];
    const float4 a1 = *(const float4*)&Alogs[((size_t)m * 512 + k * DD + d) * 8 + 4];
    aln2[0] = -__expf(a0.x) * LOG2E; aln2[1] = -__expf(a0.y) * LOG2E;
    aln2[2] = -__expf(a0.z) * LOG2E; aln2[3] = -__expf(a0.w) * LOG2E;
    aln2[4] = -__expf(a1.x) * LOG2E; aln2[5] = -__expf(a1.y) * LOG2E;
    aln2[6] = -__expf(a1.z) * LOG2E; aln2[7] = -__expf(a1.w) * LOG2E;
  }
  bool fastp = true;
#pragma unroll
  for (int n = 1; n < 8; ++n)
    fastp = fastp && (fabsf(aln2[n] - (float)(n + 1) * aln2[0]) <=
                      1e-4f * fabsf(aln2[n]) + 1e-12f);
  float wreg[8];
  {
    const float4 w0 = *(const float4*)&dt_w[((size_t)mbk * DD + d) * 8];
    const float4 w1 = *(const float4*)&dt_w[((size_t)mbk * DD + d) * 8 + 4];
    wreg[0] = w0.x; wreg[1] = w0.y; wreg[2] = w0.z; wreg[3] = w0.w;
    wreg[4] = w1.x; wreg[5] = w1.y; wreg[6] = w1.z; wreg[7] = w1.w;
  }
  const float bw = dt_b[(size_t)mbk * DD + d];
  const float dsv = Ds[(size_t)m * 512 + k * DD + d];

  const float* __restrict__ tsrc = xdbl + ((size_t)mbk * LL + seg * 64) * 24;
#pragma unroll
  for (int t = 0; t < 3; ++t) {
    const int idx = d + t * 128;
    ((float4*)slds)[idx] = ((const float4*)tsrc)[idx];
  }

  int base, step;
  seg_base_step(k, seg, base, step);
  const float* __restrict__ xsrc = xc + (size_t)mb * LL * DD + (size_t)base * DD + d;
  float* __restrict__ ydst = ysum + (size_t)mb * LL * DD + (size_t)base * DD + d;
  const ptrdiff_t sstep = (ptrdiff_t)step * DD;

  float xreg[8];
#pragma unroll
  for (int j = 0; j < 8; ++j) xreg[j] = xsrc[(ptrdiff_t)j * sstep];

  float h[8];
  {
    const float* __restrict__ hp = hin + (((size_t)mbk * SEG + seg) << 10) + d * 8;
    const float4 h0 = *(const float4*)&hp[0];
    const float4 h1 = *(const float4*)&hp[4];
    h[0] = h0.x; h[1] = h0.y; h[2] = h0.z; h[3] = h0.w;
    h[4] = h1.x; h[5] = h1.y; h[6] = h1.z; h[7] = h1.w;
  }
  __syncthreads();

  auto body = [&](auto ft) {
    constexpr bool F = decltype(ft)::value;
#pragma unroll
    for (int i = 0; i < 64; ++i) {
      const float x = xreg[i & 7];
      if (i + 8 < 64) xreg[i & 7] = xsrc[(ptrdiff_t)(i + 8) * sstep];
      const float4 t0 = *(const float4*)&slds[i * 24 + 0];
      const float4 t1 = *(const float4*)&slds[i * 24 + 4];
      float s = bw;
      s = fmaf(t0.x, wreg[0], s); s = fmaf(t0.y, wreg[1], s);
      s = fmaf(t0.z, wreg[2], s); s = fmaf(t0.w, wreg[3], s);
      s = fmaf(t1.x, wreg[4], s); s = fmaf(t1.y, wreg[5], s);
      s = fmaf(t1.z, wreg[6], s); s = fmaf(t1.w, wreg[7], s);
      const float dt = sp_(s);
      const float u = dt * x;
      float q1, q2, q3, q4, q5, q6, q7, q8;
      if constexpr (F) {
        q1 = __builtin_amdgcn_exp2f(dt * aln2[0]);
        q2 = q1 * q1; q3 = q2 * q1; q4 = q2 * q2;
        q5 = q4 * q1; q6 = q4 * q2; q7 = q4 * q3; q8 = q4 * q4;
      } else {
        q1 = __builtin_amdgcn_exp2f(dt * aln2[0]);
        q2 = __builtin_amdgcn_exp2f(dt * aln2[1]);
        q3 = __builtin_amdgcn_exp2f(dt * aln2[2]);
        q4 = __builtin_amdgcn_exp2f(dt * aln2[3]);
        q5 = __builtin_amdgcn_exp2f(dt * aln2[4]);
        q6 = __builtin_amdgcn_exp2f(dt * aln2[5]);
        q7 = __builtin_amdgcn_exp2f(dt * aln2[6]);
        q8 = __builtin_amdgcn_exp2f(dt * aln2[7]);
      }
      const float4 b0 = *(const float4*)&slds[i * 24 + 8];
      const float4 b1 = *(const float4*)&slds[i * 24 + 12];
      const float4 c0 = *(const float4*)&slds[i * 24 + 16];
      const float4 c1 = *(const float4*)&slds[i * 24 + 20];
      float y = dsv * x;
      h[0] = fmaf(h[0], q1, u * b0.x); y = fmaf(h[0], c0.x, y);
      h[1] = fmaf(h[1], q2, u * b0.y); y = fmaf(h[1], c0.y, y);
      h[2] = fmaf(h[2], q3, u * b0.z); y = fmaf(h[2], c0.z, y);
      h[3] = fmaf(h[3], q4, u * b0.w); y = fmaf(h[3], c0.w, y);
      h[4] = fmaf(h[4], q5, u * b1.x); y = fmaf(h[4], c1.x, y);
      h[5] = fmaf(h[5], q6, u * b1.y); y = fmaf(h[5], c1.y, y);
      h[6] = fmaf(h[6], q7, u * b1.z); y = fmaf(h[6], c1.z, y);
      h[7] = fmaf(h[7], q8, u * b1.w); y = fmaf(h[7], c1.w, y);
      unsafeAtomicAdd(ydst + (ptrdiff_t)i * sstep, y);
    }
  };
  if (fastp) body(BoolT<true>{}); else body(BoolT<false>{});
}

// ---------------- K6: LN(y) * silu(z) @ out_w^T -> guided[m][b][l][d] -----
// 32-row tiles, grid (128, 8)
__global__ __launch_bounds__(256) void k_outproj(
    const float* __restrict__ ysum, const float* __restrict__ xz,
    const float* __restrict__ ln_g, const float* __restrict__ ln_b,
    const float* __restrict__ out_w, float* __restrict__ guided) {
  const int lt = blockIdx.x, mb = blockIdx.y;
  const int m = mb >> 2;
  __shared__ float sv[32][132];
  __shared__ float sW[64][68];
  __shared__ float smr[32][2];
  __shared__ float sg[128], sb[128];
  const int tid = threadIdx.x;
  if (tid < 128) { sg[tid] = ln_g[m * DD + tid]; sb[tid] = ln_b[m * DD + tid]; }
  const float4* __restrict__ ysrc = (const float4*)(ysum + ((size_t)mb * LL + lt * 32) * DD);
  for (int idx = tid; idx < 1024; idx += 256)
    *(float4*)&sv[idx >> 5][(idx & 31) << 2] = ysrc[idx];
  __syncthreads();
  {
    const int l = tid >> 3, q = tid & 7;
    float s = 0.f, s2 = 0.f;
#pragma unroll
    for (int d0 = 0; d0 < 16; d0 += 4) {
      const float4 v = *(const float4*)&sv[l][q * 16 + d0];
      s += v.x + v.y + v.z + v.w;
      s2 += v.x * v.x + v.y * v.y + v.z * v.z + v.w * v.w;
    }
    s = dpp_add_<0xB1>(s); s = dpp_add_<0x4E>(s); s = dpp_add_<0x141>(s);
    s2 = dpp_add_<0xB1>(s2); s2 = dpp_add_<0x4E>(s2); s2 = dpp_add_<0x141>(s2);
    if (q == 0) {
      const float mean = s * (1.f / 128.f);
      smr[l][0] = mean;
      smr[l][1] = rsqrtf(fmaf(s2, 1.f / 128.f, -mean * mean) + 1e-5f);
    }
  }
  __syncthreads();
  {
    const int c = tid >> 1, half = tid & 1;
    const float* __restrict__ zsrc = xz + ((size_t)mb * 256 + 128 + c) * LL + lt * 32 + half * 16;
    const float g = sg[c], bb = sb[c];
#pragma unroll
    for (int i = 0; i < 16; i += 4) {
      const float4 z4 = *(const float4*)&zsrc[i];
      const float zz[4] = {z4.x, z4.y, z4.z, z4.w};
#pragma unroll
      for (int t = 0; t < 4; ++t) {
        const int l = half * 16 + i + t;
        const float v = fmaf((sv[l][c] - smr[l][0]) * smr[l][1], g, bb);
        sv[l][c] = v * silu_(zz[t]);
      }
    }
  }
  const int tc = tid & 15, tl = tid >> 4;
  const float* __restrict__ Wp = out_w + (size_t)m * DD * DD;
  float* __restrict__ dst = guided + ((size_t)mb * LL + lt * 32) * DD;
  for (int jb = 0; jb < 2; ++jb) {
    float acc[4][2] = {};
    for (int db = 0; db < 2; ++db) {
      __syncthreads();
      for (int idx = tid; idx < 64 * 16; idx += 256) {
        const int r = idx >> 4, d4 = (idx & 15) << 2;
        *(float4*)&sW[r][d4] = *(const float4*)&Wp[(size_t)(jb * 64 + r) * DD + db * 64 + d4];
      }
      __syncthreads();
#pragma unroll 4
      for (int d0 = 0; d0 < 64; d0 += 4) {
        float4 av[2], wv[4];
#pragma unroll
        for (int q = 0; q < 2; ++q) av[q] = *(const float4*)&sv[tl * 2 + q][db * 64 + d0];
#pragma unroll
        for (int j = 0; j < 4; ++j) wv[j] = *(const float4*)&sW[tc + 16 * j][d0];
#pragma unroll
        for (int j = 0; j < 4; ++j)
#pragma unroll
          for (int q = 0; q < 2; ++q)
            acc[j][q] += av[q].x * wv[j].x + av[q].y * wv[j].y + av[q].z * wv[j].z + av[q].w * wv[j].w;
      }
    }
#pragma unroll
    for (int j = 0; j < 4; ++j)
#pragma unroll
      for (int q = 0; q < 2; ++q)
        dst[(size_t)(tl * 2 + q) * DD + jb * 64 + tc + 16 * j] = acc[j][q];
  }
}

// ---------------- K7: enhance (LN -> GEMM -> +bias -> GELU -> +residual) --
// 32-row tiles, grid (128, 8)
__global__ __launch_bounds__(256) void k_enhance(
    const float* __restrict__ guided, const float* __restrict__ eg,
    const float* __restrict__ ebv, const float* __restrict__ ew,
    const float* __restrict__ ebias, const float* __restrict__ sar,
    const float* __restrict__ opt, float* __restrict__ outp) {
  const int lt = blockIdx.x, ib = blockIdx.y;
  const int i = ib >> 2, b = ib & 3;
  __shared__ float sv[32][132];
  __shared__ float sW[64][68];
  __shared__ float smr[32][2];
  __shared__ float sg[128], sb2[128], sbias[128];
  const int tid = threadIdx.x;
  if (tid < 128) {
    sg[tid] = eg[i * DD + tid];
    sb2[tid] = ebv[i * DD + tid];
    sbias[tid] = ebias[i * DD + tid];
  }
  const float4* __restrict__ gsrc =
      (const float4*)(guided + (((size_t)(1 - i) * 4 + b) * LL + lt * 32) * DD);
  for (int idx = tid; idx < 1024; idx += 256)
    *(float4*)&sv[idx >> 5][(idx & 31) << 2] = gsrc[idx];
  __syncthreads();
  {
    const int l = tid >> 3, q = tid & 7;
    float s = 0.f, s2 = 0.f;
#pragma unroll
    for (int d0 = 0; d0 < 16; d0 += 4) {
      const float4 v = *(const float4*)&sv[l][q * 16 + d0];
      s += v.x + v.y + v.z + v.w;
      s2 += v.x * v.x + v.y * v.y + v.z * v.z + v.w * v.w;
    }
    s = dpp_add_<0xB1>(s); s = dpp_add_<0x4E>(s); s = dpp_add_<0x141>(s);
    s2 = dpp_add_<0xB1>(s2); s2 = dpp_add_<0x4E>(s2); s2 = dpp_add_<0x141>(s2);
    if (q == 0) {
      const float mean = s * (1.f / 128.f);
      smr[l][0] = mean;
      smr[l][1] = rsqrtf(fmaf(s2, 1.f / 128.f, -mean * mean) + 1e-5f);
    }
  }
  __syncthreads();
  {
    const int c = tid >> 1, half = tid & 1;
    const float g = sg[c], bb = sb2[c];
#pragma unroll
    for (int i2 = 0; i2 < 16; ++i2) {
      const int l = half * 16 + i2;
      sv[l][c] = fmaf((sv[l][c] - smr[l][0]) * smr[l][1], g, bb);
    }
  }
  const int tc = tid & 15, tl = tid >> 4;
  const float* __restrict__ Wp = ew + (size_t)i * DD * DD;
  const float* __restrict__ resid = (i == 0 ? sar : opt) + ((size_t)b * LL + lt * 32) * DD;
  float* __restrict__ dst = outp + (size_t)i * (4 * LL * DD) + ((size_t)b * LL + lt * 32) * DD;
  for (int jb = 0; jb < 2; ++jb) {
    float acc[4][2] = {};
    for (int db = 0; db < 2; ++db) {
      __syncthreads();
      for (int idx = tid; idx < 64 * 16; idx += 256) {
        const int r = idx >> 4, d4 = (idx & 15) << 2;
        *(float4*)&sW[r][d4] = *(const float4*)&Wp[(size_t)(jb * 64 + r) * DD + db * 64 + d4];
      }
      __syncthreads();
#pragma unroll 4
      for (int d0 = 0; d0 < 64; d0 += 4) {
        float4 av[2], wv[4];
#pragma unroll
        for (int q = 0; q < 2; ++q) av[q] = *(const float4*)&sv[tl * 2 + q][db * 64 + d0];
#pragma unroll
        for (int j = 0; j < 4; ++j) wv[j] = *(const float4*)&sW[tc + 16 * j][d0];
#pragma unroll
        for (int j = 0; j < 4; ++j)
#pragma unroll
          for (int q = 0; q < 2; ++q)
            acc[j][q] += av[q].x * wv[j].x + av[q].y * wv[j].y + av[q].z * wv[j].z + av[q].w * wv[j].w;
      }
    }
#pragma unroll
    for (int j = 0; j < 4; ++j)
#pragma unroll
      for (int q = 0; q < 2; ++q) {
        const int col = jb * 64 + tc + 16 * j;
        const int row = tl * 2 + q;
        const float u = acc[j][q] + sbias[col];
        dst[(size_t)row * DD + col] = resid[(size_t)row * DD + col] + gelu_(u);
      }
  }
}

extern "C" void kernel_launch(void* const* d_in, const int* in_sizes, int n_in,
                              void* d_out, int out_size, void* d_ws, size_t ws_size,
                              hipStream_t stream) {
  (void)in_sizes; (void)n_in; (void)out_size; (void)ws_size;
  const float* sar    = (const float*)d_in[0];
  const float* opt    = (const float*)d_in[1];
  const float* in_w   = (const float*)d_in[2];
  const float* conv_w = (const float*)d_in[3];
  const float* conv_b = (const float*)d_in[4];
  const float* xproj_w= (const float*)d_in[5];
  const float* dt_w   = (const float*)d_in[6];
  const float* dt_b   = (const float*)d_in[7];
  const float* Alogs  = (const float*)d_in[8];
  const float* Ds     = (const float*)d_in[9];
  const float* ln_g   = (const float*)d_in[10];
  const float* ln_b   = (const float*)d_in[11];
  const float* out_w  = (const float*)d_in[12];
  const float* eg     = (const float*)d_in[13];
  const float* eb     = (const float*)d_in[14];
  const float* ew     = (const float*)d_in[15];
  const float* ebias  = (const float*)d_in[16];

  float* ws     = (float*)d_ws;
  float* xz     = ws;                  // 2*4*256*4096      = 8,388,608
  float* xc     = xz + 8388608;        // 2*4*4096*128      = 4,194,304
  float* xdbl   = xc + 4194304;        // 32*4096*24        = 3,145,728
  float* ysumb  = xdbl + 3145728;      // 2*4*4096*128      = 4,194,304
  float* guided = ysumb + 4194304;     // 2*4*4096*128      = 4,194,304
  float* hend   = guided + 4194304;    // 32*64*1024        = 2,097,152
  float* Pseg   = hend + 2097152;      // 2,097,152
  float* hin    = Pseg + 2097152;      // 2,097,152
  float* outf   = (float*)d_out;

  hipMemsetAsync(ysumb, 0, (size_t)4194304 * sizeof(float), stream);
  k_inproj <<<dim3(64, 4, 8), 256, 0, stream>>>(sar, opt, in_w, xz);
  k_conv   <<<dim3(4, 16, 8), 256, 0, stream>>>(xz, conv_w, conv_b, xc);
  k_xproj  <<<dim3(64, 4, 8), 256, 0, stream>>>(xc, xproj_w, xdbl);
  k_scan1  <<<dim3(63, 4, 8), 128, 0, stream>>>(xc, xdbl, dt_w, dt_b, Alogs, hend, Pseg);
  k_scan2  <<<dim3(128), 256, 0, stream>>>(hend, Pseg, hin);
  k_scan3  <<<dim3(64, 4, 8), 128, 0, stream>>>(xc, xdbl, dt_w, dt_b, Alogs, Ds, hin, ysumb);
  k_outproj<<<dim3(128, 8), 256, 0, stream>>>(ysumb, xz, ln_g, ln_b, out_w, guided);
  k_enhance<<<dim3(128, 8), 256, 0, stream>>>(guided, eg, eb, ew, ebias, sar, opt, outf);
}